// Round 11
// baseline (348.729 us; speedup 1.0000x reference)
//
#include <hip/hip_runtime.h>

#define DMODEL 1024
#define DFF    4096
#define SEQ    2048
#define NTOK   4096   // B*S = 2*2048
#define QKVN   3072   // fused QKV output width
#define LOG2E  1.4426950408889634f

typedef unsigned short u16;
typedef short s8v __attribute__((ext_vector_type(8)));
typedef float f4v __attribute__((ext_vector_type(4)));

__device__ __forceinline__ u16 f2bf(float f) {
  union { float f; unsigned u; } c; c.f = f;
  unsigned r = c.u + 0x7fffu + ((c.u >> 16) & 1u);
  return (u16)(r >> 16);
}
__device__ __forceinline__ float u2f(unsigned u) {
  union { unsigned u; float f; } c; c.u = u; return c.f;
}

// v_cvt_pk_bf16_f32: dst.lo = bf16(lo), dst.hi = bf16(hi)  (RNE)
__device__ __forceinline__ unsigned cvt_pk_bf16(float lo, float hi) {
  unsigned r;
  asm("v_cvt_pk_bf16_f32 %0, %1, %2" : "=v"(r) : "v"(lo), "v"(hi));
  return r;
}
__device__ __forceinline__ void pl32swap(unsigned& x, unsigned& y) {
  asm("v_permlane32_swap_b32 %0, %1" : "+v"(x), "+v"(y));
}
__device__ __forceinline__ void pl16swap(unsigned& x, unsigned& y) {
  asm("v_permlane16_swap_b32 %0, %1" : "+v"(x), "+v"(y));
}

typedef const __attribute__((address_space(1))) unsigned GAS;
typedef __attribute__((address_space(3))) unsigned LAS;
__device__ __forceinline__ void gl2lds16(const void* g, void* l) {
  __builtin_amdgcn_global_load_lds((GAS*)g, (LAS*)l, 16, 0, 0);
}

// ---------------- fused prep: 6 weight transposes (fp32->bf16, optional scale) + QKV bias concat ----------------
__device__ __forceinline__ void tr32(const float* __restrict__ W, u16* __restrict__ Wt,
                                     int K, int N, int bx, int by, float (*sh)[33],
                                     float scale) {
  int n0 = bx * 32, k0 = by * 32;
  int tx = threadIdx.x & 31, ty = threadIdx.x >> 5;
#pragma unroll
  for (int r = ty; r < 32; r += 8) sh[r][tx] = W[(size_t)(k0 + r) * N + n0 + tx];
  __syncthreads();
#pragma unroll
  for (int r = ty; r < 32; r += 8) Wt[(size_t)(n0 + r) * K + k0 + tx] = f2bf(sh[tx][r] * scale);
}

__global__ __launch_bounds__(256)
void prep(const float* __restrict__ Wq, const float* __restrict__ Wk,
          const float* __restrict__ Wv, const float* __restrict__ Wo,
          const float* __restrict__ W1, const float* __restrict__ W2,
          const float* __restrict__ bq, const float* __restrict__ bk,
          const float* __restrict__ bv,
          u16* __restrict__ wqkv_t, u16* __restrict__ wo_t,
          u16* __restrict__ w1_t, u16* __restrict__ w2_t, float* __restrict__ bqkv) {
  __shared__ float sh[32][33];
  int b = blockIdx.x;
  if (b < 1024) {
    // Wq scaled by log2(e): softmax runs in exp2 domain (scores = 1.4427 * q.k)
    tr32(Wq, wqkv_t, 1024, 1024, b & 31, b >> 5, sh, LOG2E);
  } else if (b < 2048) {
    b -= 1024; tr32(Wk, wqkv_t + (1u << 20), 1024, 1024, b & 31, b >> 5, sh, 1.0f);
  } else if (b < 3072) {
    b -= 2048; tr32(Wv, wqkv_t + (2u << 20), 1024, 1024, b & 31, b >> 5, sh, 1.0f);
  } else if (b < 4096) {
    b -= 3072; tr32(Wo, wo_t, 1024, 1024, b & 31, b >> 5, sh, 1.0f);
  } else if (b < 8192) {
    b -= 4096; tr32(W1, w1_t, 1024, 4096, b & 127, b >> 7, sh, 1.0f);  // K=1024,N=4096
  } else if (b < 12288) {
    b -= 8192; tr32(W2, w2_t, 4096, 1024, b & 31, b >> 5, sh, 1.0f);   // K=4096,N=1024
  } else {
    int t = (b - 12288) * 256 + threadIdx.x;  // 0..3071
    float v = (t < 1024) ? bq[t] * LOG2E : (t < 2048 ? bk[t - 1024] : bv[t - 2048]);
    bqkv[t] = v;
  }
}

// ---------------- LayerNorm (ddof=1, alpha/(std+eps), scalar alpha/beta) -> bf16 ----------------
__global__ __launch_bounds__(256)
void ln_bf16(const float* __restrict__ X, u16* __restrict__ Y,
             const float* __restrict__ a_p, const float* __restrict__ b_p) {
  int row = blockIdx.x;
  const float4* xr = (const float4*)(X + (size_t)row * DMODEL);
  float4 v = xr[threadIdx.x];
  float s  = v.x + v.y + v.z + v.w;
  float ss = v.x * v.x + v.y * v.y + v.z * v.z + v.w * v.w;
#pragma unroll
  for (int m = 32; m >= 1; m >>= 1) { s += __shfl_xor(s, m, 64); ss += __shfl_xor(ss, m, 64); }
  __shared__ float red[8];
  int wid = threadIdx.x >> 6, lane = threadIdx.x & 63;
  if (lane == 0) { red[wid] = s; red[4 + wid] = ss; }
  __syncthreads();
  s  = red[0] + red[1] + red[2] + red[3];
  ss = red[4] + red[5] + red[6] + red[7];
  float mean = s * (1.0f / 1024.0f);
  float var  = fmaxf((ss - s * mean) * (1.0f / 1023.0f), 0.0f);
  float k    = a_p[0] / (sqrtf(var) + 1e-6f);
  float beta = b_p[0];
  ushort4 o;
  o.x = f2bf((v.x - mean) * k + beta);
  o.y = f2bf((v.y - mean) * k + beta);
  o.z = f2bf((v.z - mean) * k + beta);
  o.w = f2bf((v.w - mean) * k + beta);
  ((ushort4*)(Y + (size_t)row * DMODEL))[threadIdx.x] = o;
}

// ---------------- fused: h += po1 (in place); n2 = LN2(h) ----------------
__global__ __launch_bounds__(256)
void ln2_comb(float* __restrict__ H, const float* __restrict__ P1,
              u16* __restrict__ Y, const float* __restrict__ a_p,
              const float* __restrict__ b_p) {
  int row = blockIdx.x;
  float4* hr = (float4*)(H + (size_t)row * DMODEL);
  float4 v = hr[threadIdx.x];
  float4 p = ((const float4*)(P1 + (size_t)row * DMODEL))[threadIdx.x];
  v.x += p.x; v.y += p.y; v.z += p.z; v.w += p.w;
  hr[threadIdx.x] = v;   // materialize h for FFN2 residual
  float s  = v.x + v.y + v.z + v.w;
  float ss = v.x * v.x + v.y * v.y + v.z * v.z + v.w * v.w;
#pragma unroll
  for (int m = 32; m >= 1; m >>= 1) { s += __shfl_xor(s, m, 64); ss += __shfl_xor(ss, m, 64); }
  __shared__ float red[8];
  int wid = threadIdx.x >> 6, lane = threadIdx.x & 63;
  if (lane == 0) { red[wid] = s; red[4 + wid] = ss; }
  __syncthreads();
  s  = red[0] + red[1] + red[2] + red[3];
  ss = red[4] + red[5] + red[6] + red[7];
  float mean = s * (1.0f / 1024.0f);
  float var  = fmaxf((ss - s * mean) * (1.0f / 1023.0f), 0.0f);
  float k    = a_p[0] / (sqrtf(var) + 1e-6f);
  float beta = b_p[0];
  ushort4 o;
  o.x = f2bf((v.x - mean) * k + beta);
  o.y = f2bf((v.y - mean) * k + beta);
  o.z = f2bf((v.z - mean) * k + beta);
  o.w = f2bf((v.w - mean) * k + beta);
  ((ushort4*)(Y + (size_t)row * DMODEL))[threadIdx.x] = o;
}

// ---------------- d_out += pf (FFN2 split-K combine; one ordered add -> deterministic) ----------------
__global__ __launch_bounds__(256)
void add2(float* __restrict__ D, const float* __restrict__ P) {
  size_t g = (size_t)blockIdx.x * 256 + threadIdx.x;
  float4 a = ((float4*)D)[g];
  float4 b = ((const float4*)P)[g];
  a.x += b.x; a.y += b.y; a.z += b.z; a.w += b.w;
  ((float4*)D)[g] = a;
}

// ---------------- 128-tile GEMM (16x16x32), single-buffer, 3 blocks/CU + XCD swizzle ----------------
// SPLIT=1: split-K over gridDim.z WITHOUT atomics: z0 writes v+bias(+resid) directly
// to Cout; z1 writes raw v to Cpart. Downstream does ONE ordered add -> deterministic.
template <int RELU, int RESID, int OUT_BF16, int SPLIT>
__global__ __launch_bounds__(256, 3)
void gemm_bt(const u16* __restrict__ A, const u16* __restrict__ Bt,
             const float* __restrict__ bias, const float* __restrict__ resid,
             void* __restrict__ Cout, float* __restrict__ Cpart,
             int M, int N, int K) {
  __shared__ __align__(16) u16 As[128 * 64];
  __shared__ __align__(16) u16 Bs[128 * 64];
  const int lane = threadIdx.x & 63, wid = threadIdx.x >> 6;
  const int llo = lane & 15, lhi = lane >> 4;

  // XCD-aware tile swizzle (proven: FETCH 143->57 MB in R2)
  const int nwg = gridDim.x * gridDim.y;
  int lin = blockIdx.y * gridDim.x + blockIdx.x;
  if ((nwg & 7) == 0) lin = (lin & 7) * (nwg >> 3) + (lin >> 3);
  const int m0 = (lin / gridDim.x) * 128, n0 = (lin % gridDim.x) * 128;

  const int wm = wid & 1, wn = wid >> 1;
  const int r8 = lane >> 3;
  const int c8 = ((lane & 7) ^ r8) * 8;   // XOR-swizzled source octet for this lane's LDS slot

  f4v acc[4][4];
  const f4v fz = {0.f, 0.f, 0.f, 0.f};
#pragma unroll
  for (int i = 0; i < 4; ++i)
#pragma unroll
    for (int j = 0; j < 4; ++j) acc[i][j] = fz;

  const u16* Ag = A  + (size_t)(m0 + r8) * K + c8;
  const u16* Bg = Bt + (size_t)(n0 + r8) * K + c8;

  const int Kp = SPLIT ? (K / gridDim.z) : K;
  const int kbeg = SPLIT ? blockIdx.z * Kp : 0;
  const int kend = kbeg + Kp;

  for (int kt = kbeg; kt < kend; kt += 64) {
#pragma unroll
    for (int c = 0; c < 4; ++c) {
      int ch = wid * 4 + c;
      gl2lds16(Ag + (size_t)(ch * 8) * K + kt, As + ch * 512);
      gl2lds16(Bg + (size_t)(ch * 8) * K + kt, Bs + ch * 512);
    }
    __syncthreads();
#pragma unroll
    for (int ks = 0; ks < 2; ++ks) {
      const int so = ((ks * 4 + lhi) ^ (llo & 7)) * 8;  // swizzled read octet
      s8v a[4], b[4];
#pragma unroll
      for (int i = 0; i < 4; ++i)
        a[i] = *(const s8v*)&As[(wm * 64 + i * 16 + llo) * 64 + so];
#pragma unroll
      for (int j = 0; j < 4; ++j)
        b[j] = *(const s8v*)&Bs[(wn * 64 + j * 16 + llo) * 64 + so];
#pragma unroll
      for (int i = 0; i < 4; ++i)
#pragma unroll
        for (int j = 0; j < 4; ++j)
          acc[i][j] = __builtin_amdgcn_mfma_f32_16x16x32_bf16(a[i], b[j], acc[i][j], 0, 0, 0);
    }
    __syncthreads();
  }
  // epilogue: C layout col=lane&15, row=(lane>>4)*4+r
#pragma unroll
  for (int j = 0; j < 4; ++j) {
    int col = n0 + wn * 64 + j * 16 + llo;
    float bv = bias[col];
#pragma unroll
    for (int i = 0; i < 4; ++i) {
      int r0 = m0 + wm * 64 + i * 16 + lhi * 4;
#pragma unroll
      for (int r = 0; r < 4; ++r) {
        size_t idx = (size_t)(r0 + r) * N + col;
        float v = acc[i][j][r];
        if (SPLIT) {
          if (blockIdx.z == 0) {
            v += bv;
            if (RESID) v += resid[idx];
            ((float*)Cout)[idx] = v;   // plain store, no RMW
          } else {
            Cpart[idx] = v;            // raw partial
          }
        } else {
          v += bv;
          if (RESID) v += resid[idx];
          if (RELU) v = fmaxf(v, 0.0f);
          if (OUT_BF16) ((u16*)Cout)[idx] = f2bf(v);
          else          ((float*)Cout)[idx] = v;
        }
      }
    }
  }
}

// ---------------- 256-tile GEMM (16x16x32), 8 waves + coalesced epilogue ----------------
// DBUF=1: double-buffered 128 KB LDS, intra-block prefetch (1 block/CU). Best for
//         UNDERFILLED grids (QKV: 192 blocks < 256 CUs) — R5/R7 proven.
// DBUF=0: single-buffer 64 KB LDS -> 2 co-resident blocks interleave stage/compute
//         phases (m114 wave-overlap). Best for FULL grids (FFN1: 256 blocks) —
//         R6 proven (FFN1 64.5 -> <52.8). Epilogue stages the wave's C in four
//         32-row quadrants through a wave-private 8 KB slice (no cross-wave sync;
//         within-wave LDS ops are in-order).
template <int RELU, int OUT_BF16, int DBUF>
__global__ __launch_bounds__(512, 2)
void gemm256(const u16* __restrict__ A, const u16* __restrict__ Bt,
             const float* __restrict__ bias, void* __restrict__ Cout,
             int M, int N, int K) {
  __shared__ __align__(16) u16 smem[DBUF ? 65536 : 32768];
  u16* As = smem;
  u16* Bs = smem + (DBUF ? 32768 : 16384);
  const int lane = threadIdx.x & 63, wid = threadIdx.x >> 6;  // 8 waves
  const int llo = lane & 15, lhi = lane >> 4;
  const int wr = wid >> 2, wc = wid & 3;   // 2M x 4N wave grid

  const int nwg = gridDim.x * gridDim.y;
  int lin = blockIdx.y * gridDim.x + blockIdx.x;
  if ((nwg & 7) == 0) lin = (lin & 7) * (nwg >> 3) + (lin >> 3);
  const int m0 = (lin / gridDim.x) * 256, n0 = (lin % gridDim.x) * 256;

  const int r8 = lane >> 3;
  const int c8 = ((lane & 7) ^ r8) * 8;   // XOR-swizzled source octet

  f4v acc[8][4];
  const f4v fz = {0.f, 0.f, 0.f, 0.f};
#pragma unroll
  for (int i = 0; i < 8; ++i)
#pragma unroll
    for (int j = 0; j < 4; ++j) acc[i][j] = fz;

  const u16* Ag = A  + (size_t)(m0 + r8) * K + c8;
  const u16* Bg = Bt + (size_t)(n0 + r8) * K + c8;
  const int nk = K >> 6;

  auto stage = [&](int buf, int kt) {
#pragma unroll
    for (int c = 0; c < 4; ++c) {
      int ch = wid * 4 + c;
      gl2lds16(Ag + (size_t)(ch * 8) * K + kt, As + buf * 16384 + ch * 512);
      gl2lds16(Bg + (size_t)(ch * 8) * K + kt, Bs + buf * 16384 + ch * 512);
    }
  };
  auto compute = [&](int buf) {
#pragma unroll
    for (int ks = 0; ks < 2; ++ks) {
      const int so = ((ks * 4 + lhi) ^ (llo & 7)) * 8;  // swizzled read octet
      s8v b[4];
#pragma unroll
      for (int j = 0; j < 4; ++j)
        b[j] = *(const s8v*)&Bs[buf * 16384 + (wc * 64 + j * 16 + llo) * 64 + so];
#pragma unroll
      for (int i = 0; i < 8; ++i) {
        s8v a = *(const s8v*)&As[buf * 16384 + (wr * 128 + i * 16 + llo) * 64 + so];
#pragma unroll
        for (int j = 0; j < 4; ++j)
          acc[i][j] = __builtin_amdgcn_mfma_f32_16x16x32_bf16(a, b[j], acc[i][j], 0, 0, 0);
      }
    }
  };

  if (DBUF) {
    stage(0, 0);
    __syncthreads();  // tile 0 resident (vmcnt(0) drained)
    int cur = 0;
    for (int t = 0; t < nk; ++t) {
      if (t + 1 < nk) stage(cur ^ 1, (t + 1) * 64);  // prefetch BEFORE compute
      compute(cur);
      __syncthreads();  // prefetch drain lands AFTER compute; safe buffer swap
      cur ^= 1;
    }
  } else {
    for (int t = 0; t < nk; ++t) {
      stage(0, t * 64);
      __syncthreads();  // tile resident
      compute(0);
      __syncthreads();  // all reads done before next stage overwrites
    }
  }

  if (OUT_BF16) {
    if (DBUF) {
      // stage C into own 16 KB LDS slice [128 rows][64 cols], XOR col-swizzle
      u16* ep = smem + wid * 8192;   // all waves past final barrier; own region only
#pragma unroll
      for (int j = 0; j < 4; ++j) {
        float bv = bias[n0 + wc * 64 + j * 16 + llo];
#pragma unroll
        for (int i = 0; i < 8; ++i) {
#pragma unroll
          for (int r = 0; r < 4; ++r) {
            int row = i * 16 + lhi * 4 + r;
            int col = j * 16 + llo;
            float v = acc[i][j][r] + bv;
            if (RELU) v = fmaxf(v, 0.0f);
            ep[row * 64 + (col ^ ((row & 7) * 8))] = f2bf(v);
          }
        }
      }
      // coalesced read-back + 16 B/lane stores (8 lanes = full 128 B line)
      const int c0 = (lane & 7) * 8;
#pragma unroll
      for (int p = 0; p < 16; ++p) {
        int row = p * 8 + (lane >> 3);
        s8v vv = *(const s8v*)&ep[row * 64 + (c0 ^ ((row & 7) * 8))];
        *(s8v*)((u16*)Cout + (size_t)(m0 + wr * 128 + row) * N + n0 + wc * 64 + c0) = vv;
      }
    } else {
      // 64 KB pool: wave-private 8 KB slice, 4 quadrants of 32 rows each
      u16* ep = smem + wid * 4096;
      const int c0 = (lane & 7) * 8;
      float bvj[4];
#pragma unroll
      for (int j = 0; j < 4; ++j) bvj[j] = bias[n0 + wc * 64 + j * 16 + llo];
#pragma unroll
      for (int q = 0; q < 4; ++q) {
#pragma unroll
        for (int j = 0; j < 4; ++j) {
#pragma unroll
          for (int ii = 0; ii < 2; ++ii) {
            int i = q * 2 + ii;
#pragma unroll
            for (int r = 0; r < 4; ++r) {
              int rl = ii * 16 + lhi * 4 + r;        // [0,32)
              int col = j * 16 + llo;
              float v = acc[i][j][r] + bvj[j];
              if (RELU) v = fmaxf(v, 0.0f);
              ep[rl * 64 + (col ^ ((rl & 7) * 8))] = f2bf(v);
            }
          }
        }
#pragma unroll
        for (int p = 0; p < 4; ++p) {
          int rl = p * 8 + (lane >> 3);
          s8v vv = *(const s8v*)&ep[rl * 64 + (c0 ^ ((rl & 7) * 8))];
          *(s8v*)((u16*)Cout + (size_t)(m0 + wr * 128 + q * 32 + rl) * N + n0 + wc * 64 + c0) = vv;
        }
      }
    }
  } else {
    // fp32 path (unused currently): original per-element stores
#pragma unroll
    for (int j = 0; j < 4; ++j) {
      int col = n0 + wc * 64 + j * 16 + llo;
      float bv = bias[col];
#pragma unroll
      for (int i = 0; i < 8; ++i) {
        int r0 = m0 + wr * 128 + i * 16 + lhi * 4;
#pragma unroll
        for (int r = 0; r < 4; ++r) {
          size_t idx = (size_t)(r0 + r) * N + col;
          float v = acc[i][j][r] + bv;
          if (RELU) v = fmaxf(v, 0.0f);
          ((float*)Cout)[idx] = v;
        }
      }
    }
  }
}

// ---------------- flash attention, split-KV x2, IN-REGISTER softmax (R7 verified) ----------------
// + T5 setprio around MFMA clusters (R10 verified: part of the -7.5 us win)
__global__ __launch_bounds__(256, 3)
void flash_attn(const u16* __restrict__ QKV, u16* __restrict__ Pacc,
                float* __restrict__ Pml) {
  // LDS pool: Ks[128][64] swizzled octets (Q tile staged here first), Vt[64][136]
  __shared__ __align__(16) u16 smem[16896];
  u16* Ks = smem;          // [128][64]
  u16* Vt = smem + 8192;   // [64][136]

  const int tid = threadIdx.x;
  const int lane = tid & 63, wid = tid >> 6;
  const int llo = lane & 15, lhi = lane >> 4;
  int lin = blockIdx.y * 16 + blockIdx.x;       // 512 per z-slab, %8==0
  lin = (lin & 7) * 64 + (lin >> 3);            // bijective XCD swizzle
  const int qt = lin & 15, bh = lin >> 4, z = blockIdx.z;
  const int b = bh >> 4, h = bh & 15;
  const int LDM = QKVN;
  const size_t base = (size_t)b * SEQ * LDM + h * 64;
  const u16* Qb = QKV + base + (size_t)qt * 128 * LDM;          // Q cols [0,1024)
  const u16* Kb = QKV + base + 1024;                            // K cols
  const u16* Vb = QKV + base + 2048;                            // V cols
  const int r8 = lane >> 3;
  const int c8 = ((lane & 7) ^ r8) * 8;  // swizzled source octet

  // stage Q tile into Ks region (DMA, swizzled), pull to regs, then release
#pragma unroll
  for (int c = 0; c < 4; ++c) {
    int ch = wid * 4 + c;
    gl2lds16(Qb + (size_t)(ch * 8 + r8) * LDM + c8, Ks + ch * 512);
  }
  __syncthreads();
  s8v qf[2][2];
#pragma unroll
  for (int mb = 0; mb < 2; ++mb)
#pragma unroll
    for (int ks = 0; ks < 2; ++ks)
      qf[mb][ks] = *(const s8v*)&Ks[(wid * 32 + mb * 16 + llo) * 64 +
                                    (((ks * 4 + lhi) ^ (llo & 7)) * 8)];
  __syncthreads();  // all qf reads done before K staging overwrites

  f4v accO[2][4];
  float l_run[2] = {0.f, 0.f};  // per-lane partial row sums (this lane's 32 keys/tile)
  const f4v fz = {0.f, 0.f, 0.f, 0.f};
#pragma unroll
  for (int mb = 0; mb < 2; ++mb)
#pragma unroll
    for (int db = 0; db < 4; ++db) accO[mb][db] = fz;

  for (int kt = z * 8; kt < z * 8 + 8; ++kt) {
    // stage K (DMA, swizzled)
#pragma unroll
    for (int c = 0; c < 4; ++c) {
      int ch = wid * 4 + c;
      gl2lds16(Kb + (size_t)(kt * 128 + ch * 8 + r8) * LDM + c8, Ks + ch * 512);
    }
    // stage V transposed: wave-uniform d-octet, lane = key pair -> conflict-free b32 writes
#pragma unroll
    for (int it = 0; it < 2; ++it) {
      int o  = wid + it * 4;                  // d-octet, uniform per wave
      int k2 = lane * 2;                      // key pair
      const u16* vp = Vb + (size_t)(kt * 128 + k2) * LDM + o * 8;
      s8v v0 = *(const s8v*)vp;
      s8v v1 = *(const s8v*)(vp + LDM);
      const u16* e0 = (const u16*)&v0;
      const u16* e1 = (const u16*)&v1;
#pragma unroll
      for (int j = 0; j < 8; ++j) {
        unsigned pk = (unsigned)e0[j] | ((unsigned)e1[j] << 16);
        *(unsigned*)&Vt[(o * 8 + j) * 136 + k2] = pk;
      }
    }
    __syncthreads();

    // swapped QK^T per 32-key block + in-register softmax/pack
    s8v pa[2][4];  // [mb][ksb] PV A-fragments
#pragma unroll
    for (int ksb = 0; ksb < 4; ++ksb) {
      f4v sA[2], sB[2];  // score tiles nb=2*ksb, 2*ksb+1  (only 16 f32 live)
#pragma unroll
      for (int mb = 0; mb < 2; ++mb) { sA[mb] = fz; sB[mb] = fz; }
#pragma unroll
      for (int ks = 0; ks < 2; ++ks) {
        const int so = ((ks * 4 + lhi) ^ (llo & 7)) * 8;
        s8v kfA = *(const s8v*)&Ks[((ksb * 2 + 0) * 16 + llo) * 64 + so];
        s8v kfB = *(const s8v*)&Ks[((ksb * 2 + 1) * 16 + llo) * 64 + so];
        __builtin_amdgcn_s_setprio(1);
#pragma unroll
        for (int mb = 0; mb < 2; ++mb) {
          sA[mb] = __builtin_amdgcn_mfma_f32_16x16x32_bf16(kfA, qf[mb][ks], sA[mb], 0, 0, 0);
          sB[mb] = __builtin_amdgcn_mfma_f32_16x16x32_bf16(kfB, qf[mb][ks], sB[mb], 0, 0, 0);
        }
        __builtin_amdgcn_s_setprio(0);
      }
#pragma unroll
      for (int mb = 0; mb < 2; ++mb) {
        float pA0 = __builtin_amdgcn_exp2f(sA[mb][0]);
        float pA1 = __builtin_amdgcn_exp2f(sA[mb][1]);
        float pA2 = __builtin_amdgcn_exp2f(sA[mb][2]);
        float pA3 = __builtin_amdgcn_exp2f(sA[mb][3]);
        float pB0 = __builtin_amdgcn_exp2f(sB[mb][0]);
        float pB1 = __builtin_amdgcn_exp2f(sB[mb][1]);
        float pB2 = __builtin_amdgcn_exp2f(sB[mb][2]);
        float pB3 = __builtin_amdgcn_exp2f(sB[mb][3]);
        l_run[mb] += ((pA0 + pA1) + (pA2 + pA3)) + ((pB0 + pB1) + (pB2 + pB3));
        // pack to bf16 pairs: a* = tile 2ksb (keys 4*lhi+{0..3}), b* = tile 2ksb+1
        unsigned a0 = cvt_pk_bf16(pA0, pA1), a1 = cvt_pk_bf16(pA2, pA3);
        unsigned b0 = cvt_pk_bf16(pB0, pB1), b1 = cvt_pk_bf16(pB2, pB3);
        // redistribute across lhi groups into A-fragment words:
        // after p32+p16: a0 -> word0 (keys 8lhi+0,1), b0 -> word2 (8lhi+4,5)
        //               a1 -> word1 (keys 8lhi+2,3), b1 -> word3 (8lhi+6,7)
        pl32swap(a0, b0); pl16swap(a0, b0);
        pl32swap(a1, b1); pl16swap(a1, b1);
        union { unsigned u[4]; s8v v; } pk;
        pk.u[0] = a0; pk.u[1] = a1; pk.u[2] = b0; pk.u[3] = b1;
        pa[mb][ksb] = pk.v;
      }
    }

    // O += P @ V
#pragma unroll
    for (int ks = 0; ks < 4; ++ks) {
      s8v vb2[4];
#pragma unroll
      for (int db = 0; db < 4; ++db)
        vb2[db] = *(const s8v*)&Vt[(db * 16 + llo) * 136 + ks * 32 + lhi * 8];
      __builtin_amdgcn_s_setprio(1);
#pragma unroll
      for (int mb = 0; mb < 2; ++mb)
#pragma unroll
        for (int db = 0; db < 4; ++db)
          accO[mb][db] = __builtin_amdgcn_mfma_f32_16x16x32_bf16(pa[mb][ks], vb2[db], accO[mb][db], 0, 0, 0);
      __builtin_amdgcn_s_setprio(0);
    }
    __syncthreads();  // before next stage overwrites Ks/Vt
  }

  // epilogue: reduce l across the 4 lhi key-groups, write bf16 partial acc + fp32 l
#pragma unroll
  for (int mb = 0; mb < 2; ++mb) {
    l_run[mb] += __shfl_xor(l_run[mb], 16, 64);
    l_run[mb] += __shfl_xor(l_run[mb], 32, 64);
  }
#pragma unroll
  for (int mb = 0; mb < 2; ++mb) {
    int row0 = qt * 128 + wid * 32 + mb * 16;
    size_t ibase = (size_t)(z * 32 + bh) * SEQ + row0;
    if (lane < 16) Pml[ibase + lane] = l_run[mb];   // lhi==0 lanes, query=row0+llo
#pragma unroll
    for (int r = 0; r < 4; ++r) {
      size_t irow = ibase + lhi * 4 + r;
#pragma unroll
      for (int db = 0; db < 4; ++db)
        Pacc[irow * 64 + db * 16 + llo] = f2bf(accO[mb][db][r]);
    }
  }
}

// ---------------- combine the two KV splits -> ctx (bf16 [tok][1024]), 8 B/thread ----------------
__global__ __launch_bounds__(256)
void attn_combine(const u16* __restrict__ Pacc, const float* __restrict__ Pml,
                  u16* __restrict__ ctx) {
  int g = blockIdx.x * 256 + threadIdx.x;  // quad id; 32*2048*16 total
  int d4 = g & 15;                         // quad of d (4 values, 8 B)
  int row = (g >> 4) & (SEQ - 1);
  int bh = g >> 15;
  int b = bh >> 4, h = bh & 15;
  size_t i0 = (size_t)bh * SEQ + row;
  size_t i1 = (size_t)(32 + bh) * SEQ + row;
  float inv = 1.0f / (Pml[i0] + Pml[i1]);
  uint2 pa = ((const uint2*)Pacc)[i0 * 16 + d4];
  uint2 pb = ((const uint2*)Pacc)[i1 * 16 + d4];
  float lo0 = u2f(pa.x << 16) + u2f(pb.x << 16);
  float hi0 = u2f(pa.x & 0xffff0000u) + u2f(pb.x & 0xffff0000u);
  float lo1 = u2f(pa.y << 16) + u2f(pb.y << 16);
  float hi1 = u2f(pa.y & 0xffff0000u) + u2f(pb.y & 0xffff0000u);
  uint2 o;
  o.x = (unsigned)f2bf(lo0 * inv) | ((unsigned)f2bf(hi0 * inv) << 16);
  o.y = (unsigned)f2bf(lo1 * inv) | ((unsigned)f2bf(hi1 * inv) << 16);
  ((uint2*)ctx)[(size_t)(b * SEQ + row) * (DMODEL / 4) + h * 16 + d4] = o;
}

// ---------------- orchestration ----------------
extern "C" void kernel_launch(void* const* d_in, const int* in_sizes, int n_in,
                              void* d_out, int out_size, void* d_ws, size_t ws_size,
                              hipStream_t stream) {
  const float* x   = (const float*)d_in[0];
  const float* Wq  = (const float*)d_in[1];  const float* bq = (const float*)d_in[2];
  const float* Wk  = (const float*)d_in[3];  const float* bk = (const float*)d_in[4];
  const float* Wv  = (const float*)d_in[5];  const float* bv = (const float*)d_in[6];
  const float* Wo  = (const float*)d_in[7];  const float* bo = (const float*)d_in[8];
  const float* W1  = (const float*)d_in[9];  const float* b1 = (const float*)d_in[10];
  const float* W2  = (const float*)d_in[11]; const float* b2 = (const float*)d_in[12];
  const float* l1a = (const float*)d_in[13]; const float* l1b = (const float*)d_in[14];
  const float* l2a = (const float*)d_in[15]; const float* l2b = (const float*)d_in[16];

  char* ws = (char*)d_ws;
  const size_t MB = 1u << 20;
  // weights 0-25 MB
  u16*   wqkv_t = (u16*)(ws + 0);          // [3072][1024] bf16: 6 MB
  u16*   wo_t   = (u16*)(ws + 6 * MB);     // [1024][1024]: 2 MB
  u16*   w1_t   = (u16*)(ws + 8 * MB);     // [4096][1024]: 8 MB
  u16*   w2_t   = (u16*)(ws + 16 * MB);    // [1024][4096]: 8 MB
  float* bqkv   = (float*)(ws + 24 * MB);  // 3072 floats
  // activations (time-multiplexed; max 97.5 MB — proven-safe footprint)
  u16*   xn1    = (u16*)(ws + 25 * MB);    // [4096][1024] bf16: 8 MB (ln1 -> QKV)
  u16*   qkv    = (u16*)(ws + 33 * MB);    // [4096][3072] bf16: 24 MB (QKV -> flash)
  u16*   Pacc   = (u16*)(ws + 57 * MB);    // [2][32][2048][64] bf16: 16 MB (flash -> combine)
  float* Pml    = (float*)(ws + 73 * MB);  // [2][32][2048] fp32: 0.5 MB
  u16*   ctx    = (u16*)(ws + 73 * MB + MB / 2);  // [4096][1024] bf16: 8 MB (combine -> O-proj)
  float* hgm    = (float*)(ws + 57 * MB);  // h fp32 16 MB (O-proj z0 direct; Pacc dead)
  float* po1    = (float*)(ws + 25 * MB);  // O-proj z1 partial fp32 16 MB (xn1+qkv dead)
  u16*   n2     = (u16*)(ws + 73 * MB + MB / 2);  // LN2 out 8 MB (ctx dead after O-proj)
  u16*   mid    = (u16*)(ws + 25 * MB);    // [4096][4096] bf16 32 MB (po1 dead)
  float* pf     = (float*)(ws + 73 * MB + MB / 2);  // FFN2 z1 partial 16 MB (n2/Pml dead)

  dim3 blk(256);

  // fused weight transposes + bias concat (Wq/bq pre-scaled by log2e for exp2-domain softmax)
  prep<<<dim3(12300), blk, 0, stream>>>(Wq, Wk, Wv, Wo, W1, W2, bq, bk, bv,
                                        wqkv_t, wo_t, w1_t, w2_t, bqkv);

  // LN1
  ln_bf16<<<NTOK, blk, 0, stream>>>(x, xn1, l1a, l1b);

  // fused QKV projection: [4096,1024] x [1024,3072] -> [4096,3072]
  // 192 blocks (< 256 CUs) -> DBUF=1 (intra-block prefetch; R7-proven for underfill)
  gemm256<0, 1, 1><<<dim3(12, 16), dim3(512), 0, stream>>>(xn1, wqkv_t, bqkv, qkv,
                                                           NTOK, QKVN, DMODEL);

  // attention, split-KV x2 -> bf16 partials, then combine
  flash_attn<<<dim3(16, 32, 2), blk, 0, stream>>>(qkv, Pacc, Pml);
  attn_combine<<<dim3(4096), blk, 0, stream>>>(Pacc, Pml, ctx);

  // O projection + residual, split-K x2 WITHOUT atomics:
  // z0 -> hgm = ctx@Wo(K-half0) + bo + x ; z1 -> po1 = ctx@Wo(K-half1)
  gemm_bt<0, 1, 0, 1><<<dim3(8, 32, 2), blk, 0, stream>>>(ctx, wo_t, bo, x, hgm, po1,
                                                          NTOK, DMODEL, DMODEL);

  // fused: h = hgm + po1 (in place, one ordered add -> deterministic); n2 = LN2(h)
  ln2_comb<<<NTOK, blk, 0, stream>>>(hgm, po1, n2, l2a, l2b);

  // FFN1: relu(n2 @ W1 + b1) -> bf16
  // 256 blocks (perfect fill) -> DBUF=0 (2 blocks/CU co-residency; R6-proven for full grids)
  gemm256<1, 1, 0><<<dim3(16, 16), dim3(512), 0, stream>>>(n2, w1_t, b1, mid,
                                                           NTOK, DFF, DMODEL);

  // FFN2 split-K x2 WITHOUT atomics: z0 -> d_out = mid@W2(half0) + b2 + h ; z1 -> pf
  gemm_bt<0, 1, 0, 1><<<dim3(8, 32, 2), blk, 0, stream>>>(mid, w2_t, b2, hgm,
                                                          (float*)d_out, pf,
                                                          NTOK, DMODEL, DFF);

  // d_out += pf  (single ordered add per element -> bitwise deterministic)
  add2<<<dim3(4096), blk, 0, stream>>>((float*)d_out, pf);
}

// Round 12
// 348.149 us; speedup vs baseline: 1.0017x; 1.0017x over previous
//
#include <hip/hip_runtime.h>

#define DMODEL 1024
#define DFF    4096
#define SEQ    2048
#define NTOK   4096   // B*S = 2*2048
#define QKVN   3072   // fused QKV output width
#define LOG2E  1.4426950408889634f

typedef unsigned short u16;
typedef short s8v __attribute__((ext_vector_type(8)));
typedef float f4v __attribute__((ext_vector_type(4)));

__device__ __forceinline__ u16 f2bf(float f) {
  union { float f; unsigned u; } c; c.f = f;
  unsigned r = c.u + 0x7fffu + ((c.u >> 16) & 1u);
  return (u16)(r >> 16);
}
__device__ __forceinline__ float u2f(unsigned u) {
  union { unsigned u; float f; } c; c.u = u; return c.f;
}

// v_cvt_pk_bf16_f32: dst.lo = bf16(lo), dst.hi = bf16(hi)  (RNE)
__device__ __forceinline__ unsigned cvt_pk_bf16(float lo, float hi) {
  unsigned r;
  asm("v_cvt_pk_bf16_f32 %0, %1, %2" : "=v"(r) : "v"(lo), "v"(hi));
  return r;
}
__device__ __forceinline__ void pl32swap(unsigned& x, unsigned& y) {
  asm("v_permlane32_swap_b32 %0, %1" : "+v"(x), "+v"(y));
}
__device__ __forceinline__ void pl16swap(unsigned& x, unsigned& y) {
  asm("v_permlane16_swap_b32 %0, %1" : "+v"(x), "+v"(y));
}

typedef const __attribute__((address_space(1))) unsigned GAS;
typedef __attribute__((address_space(3))) unsigned LAS;
__device__ __forceinline__ void gl2lds16(const void* g, void* l) {
  __builtin_amdgcn_global_load_lds((GAS*)g, (LAS*)l, 16, 0, 0);
}

// ---------------- fused prep: 6 weight transposes (fp32->bf16, optional scale) + QKV bias concat ----------------
__device__ __forceinline__ void tr32(const float* __restrict__ W, u16* __restrict__ Wt,
                                     int K, int N, int bx, int by, float (*sh)[33],
                                     float scale) {
  int n0 = bx * 32, k0 = by * 32;
  int tx = threadIdx.x & 31, ty = threadIdx.x >> 5;
#pragma unroll
  for (int r = ty; r < 32; r += 8) sh[r][tx] = W[(size_t)(k0 + r) * N + n0 + tx];
  __syncthreads();
#pragma unroll
  for (int r = ty; r < 32; r += 8) Wt[(size_t)(n0 + r) * K + k0 + tx] = f2bf(sh[tx][r] * scale);
}

__global__ __launch_bounds__(256)
void prep(const float* __restrict__ Wq, const float* __restrict__ Wk,
          const float* __restrict__ Wv, const float* __restrict__ Wo,
          const float* __restrict__ W1, const float* __restrict__ W2,
          const float* __restrict__ bq, const float* __restrict__ bk,
          const float* __restrict__ bv,
          u16* __restrict__ wqkv_t, u16* __restrict__ wo_t,
          u16* __restrict__ w1_t, u16* __restrict__ w2_t, float* __restrict__ bqkv) {
  __shared__ float sh[32][33];
  int b = blockIdx.x;
  if (b < 1024) {
    // Wq scaled by log2(e): softmax runs in exp2 domain (scores = 1.4427 * q.k)
    tr32(Wq, wqkv_t, 1024, 1024, b & 31, b >> 5, sh, LOG2E);
  } else if (b < 2048) {
    b -= 1024; tr32(Wk, wqkv_t + (1u << 20), 1024, 1024, b & 31, b >> 5, sh, 1.0f);
  } else if (b < 3072) {
    b -= 2048; tr32(Wv, wqkv_t + (2u << 20), 1024, 1024, b & 31, b >> 5, sh, 1.0f);
  } else if (b < 4096) {
    b -= 3072; tr32(Wo, wo_t, 1024, 1024, b & 31, b >> 5, sh, 1.0f);
  } else if (b < 8192) {
    b -= 4096; tr32(W1, w1_t, 1024, 4096, b & 127, b >> 7, sh, 1.0f);  // K=1024,N=4096
  } else if (b < 12288) {
    b -= 8192; tr32(W2, w2_t, 4096, 1024, b & 31, b >> 5, sh, 1.0f);   // K=4096,N=1024
  } else {
    int t = (b - 12288) * 256 + threadIdx.x;  // 0..3071
    float v = (t < 1024) ? bq[t] * LOG2E : (t < 2048 ? bk[t - 1024] : bv[t - 2048]);
    bqkv[t] = v;
  }
}

// ---------------- LayerNorm (ddof=1, alpha/(std+eps), scalar alpha/beta) -> bf16 ----------------
__global__ __launch_bounds__(256)
void ln_bf16(const float* __restrict__ X, u16* __restrict__ Y,
             const float* __restrict__ a_p, const float* __restrict__ b_p) {
  int row = blockIdx.x;
  const float4* xr = (const float4*)(X + (size_t)row * DMODEL);
  float4 v = xr[threadIdx.x];
  float s  = v.x + v.y + v.z + v.w;
  float ss = v.x * v.x + v.y * v.y + v.z * v.z + v.w * v.w;
#pragma unroll
  for (int m = 32; m >= 1; m >>= 1) { s += __shfl_xor(s, m, 64); ss += __shfl_xor(ss, m, 64); }
  __shared__ float red[8];
  int wid = threadIdx.x >> 6, lane = threadIdx.x & 63;
  if (lane == 0) { red[wid] = s; red[4 + wid] = ss; }
  __syncthreads();
  s  = red[0] + red[1] + red[2] + red[3];
  ss = red[4] + red[5] + red[6] + red[7];
  float mean = s * (1.0f / 1024.0f);
  float var  = fmaxf((ss - s * mean) * (1.0f / 1023.0f), 0.0f);
  float k    = a_p[0] / (sqrtf(var) + 1e-6f);
  float beta = b_p[0];
  ushort4 o;
  o.x = f2bf((v.x - mean) * k + beta);
  o.y = f2bf((v.y - mean) * k + beta);
  o.z = f2bf((v.z - mean) * k + beta);
  o.w = f2bf((v.w - mean) * k + beta);
  ((ushort4*)(Y + (size_t)row * DMODEL))[threadIdx.x] = o;
}

// ---------------- fused: h += po1 (in place); n2 = LN2(h) ----------------
__global__ __launch_bounds__(256)
void ln2_comb(float* __restrict__ H, const float* __restrict__ P1,
              u16* __restrict__ Y, const float* __restrict__ a_p,
              const float* __restrict__ b_p) {
  int row = blockIdx.x;
  float4* hr = (float4*)(H + (size_t)row * DMODEL);
  float4 v = hr[threadIdx.x];
  float4 p = ((const float4*)(P1 + (size_t)row * DMODEL))[threadIdx.x];
  v.x += p.x; v.y += p.y; v.z += p.z; v.w += p.w;
  hr[threadIdx.x] = v;   // materialize h for FFN2 residual
  float s  = v.x + v.y + v.z + v.w;
  float ss = v.x * v.x + v.y * v.y + v.z * v.z + v.w * v.w;
#pragma unroll
  for (int m = 32; m >= 1; m >>= 1) { s += __shfl_xor(s, m, 64); ss += __shfl_xor(ss, m, 64); }
  __shared__ float red[8];
  int wid = threadIdx.x >> 6, lane = threadIdx.x & 63;
  if (lane == 0) { red[wid] = s; red[4 + wid] = ss; }
  __syncthreads();
  s  = red[0] + red[1] + red[2] + red[3];
  ss = red[4] + red[5] + red[6] + red[7];
  float mean = s * (1.0f / 1024.0f);
  float var  = fmaxf((ss - s * mean) * (1.0f / 1023.0f), 0.0f);
  float k    = a_p[0] / (sqrtf(var) + 1e-6f);
  float beta = b_p[0];
  ushort4 o;
  o.x = f2bf((v.x - mean) * k + beta);
  o.y = f2bf((v.y - mean) * k + beta);
  o.z = f2bf((v.z - mean) * k + beta);
  o.w = f2bf((v.w - mean) * k + beta);
  ((ushort4*)(Y + (size_t)row * DMODEL))[threadIdx.x] = o;
}

// ---------------- d_out += pf (FFN2 split-K combine; one ordered add -> deterministic) ----------------
__global__ __launch_bounds__(256)
void add2(float* __restrict__ D, const float* __restrict__ P) {
  size_t g = (size_t)blockIdx.x * 256 + threadIdx.x;
  float4 a = ((float4*)D)[g];
  float4 b = ((const float4*)P)[g];
  a.x += b.x; a.y += b.y; a.z += b.z; a.w += b.w;
  ((float4*)D)[g] = a;
}

// ---------------- 128-tile GEMM (16x16x32), single-buffer, 3 blocks/CU + XCD swizzle ----------------
// SPLIT=1: split-K over gridDim.z WITHOUT atomics: z0 writes v+bias(+resid) directly
// to Cout; z1 writes raw v to Cpart. Downstream does ONE ordered add -> deterministic.
template <int RELU, int RESID, int OUT_BF16, int SPLIT>
__global__ __launch_bounds__(256, 3)
void gemm_bt(const u16* __restrict__ A, const u16* __restrict__ Bt,
             const float* __restrict__ bias, const float* __restrict__ resid,
             void* __restrict__ Cout, float* __restrict__ Cpart,
             int M, int N, int K) {
  __shared__ __align__(16) u16 As[128 * 64];
  __shared__ __align__(16) u16 Bs[128 * 64];
  const int lane = threadIdx.x & 63, wid = threadIdx.x >> 6;
  const int llo = lane & 15, lhi = lane >> 4;

  // XCD-aware tile swizzle (proven: FETCH 143->57 MB in R2)
  const int nwg = gridDim.x * gridDim.y;
  int lin = blockIdx.y * gridDim.x + blockIdx.x;
  if ((nwg & 7) == 0) lin = (lin & 7) * (nwg >> 3) + (lin >> 3);
  const int m0 = (lin / gridDim.x) * 128, n0 = (lin % gridDim.x) * 128;

  const int wm = wid & 1, wn = wid >> 1;
  const int r8 = lane >> 3;
  const int c8 = ((lane & 7) ^ r8) * 8;   // XOR-swizzled source octet for this lane's LDS slot

  f4v acc[4][4];
  const f4v fz = {0.f, 0.f, 0.f, 0.f};
#pragma unroll
  for (int i = 0; i < 4; ++i)
#pragma unroll
    for (int j = 0; j < 4; ++j) acc[i][j] = fz;

  const u16* Ag = A  + (size_t)(m0 + r8) * K + c8;
  const u16* Bg = Bt + (size_t)(n0 + r8) * K + c8;

  const int Kp = SPLIT ? (K / gridDim.z) : K;
  const int kbeg = SPLIT ? blockIdx.z * Kp : 0;
  const int kend = kbeg + Kp;

  for (int kt = kbeg; kt < kend; kt += 64) {
#pragma unroll
    for (int c = 0; c < 4; ++c) {
      int ch = wid * 4 + c;
      gl2lds16(Ag + (size_t)(ch * 8) * K + kt, As + ch * 512);
      gl2lds16(Bg + (size_t)(ch * 8) * K + kt, Bs + ch * 512);
    }
    __syncthreads();
#pragma unroll
    for (int ks = 0; ks < 2; ++ks) {
      const int so = ((ks * 4 + lhi) ^ (llo & 7)) * 8;  // swizzled read octet
      s8v a[4], b[4];
#pragma unroll
      for (int i = 0; i < 4; ++i)
        a[i] = *(const s8v*)&As[(wm * 64 + i * 16 + llo) * 64 + so];
#pragma unroll
      for (int j = 0; j < 4; ++j)
        b[j] = *(const s8v*)&Bs[(wn * 64 + j * 16 + llo) * 64 + so];
#pragma unroll
      for (int i = 0; i < 4; ++i)
#pragma unroll
        for (int j = 0; j < 4; ++j)
          acc[i][j] = __builtin_amdgcn_mfma_f32_16x16x32_bf16(a[i], b[j], acc[i][j], 0, 0, 0);
    }
    __syncthreads();
  }
  // epilogue: C layout col=lane&15, row=(lane>>4)*4+r
#pragma unroll
  for (int j = 0; j < 4; ++j) {
    int col = n0 + wn * 64 + j * 16 + llo;
    float bv = bias[col];
#pragma unroll
    for (int i = 0; i < 4; ++i) {
      int r0 = m0 + wm * 64 + i * 16 + lhi * 4;
#pragma unroll
      for (int r = 0; r < 4; ++r) {
        size_t idx = (size_t)(r0 + r) * N + col;
        float v = acc[i][j][r];
        if (SPLIT) {
          if (blockIdx.z == 0) {
            v += bv;
            if (RESID) v += resid[idx];
            ((float*)Cout)[idx] = v;   // plain store, no RMW
          } else {
            Cpart[idx] = v;            // raw partial
          }
        } else {
          v += bv;
          if (RESID) v += resid[idx];
          if (RELU) v = fmaxf(v, 0.0f);
          if (OUT_BF16) ((u16*)Cout)[idx] = f2bf(v);
          else          ((float*)Cout)[idx] = v;
        }
      }
    }
  }
}

// ---------------- 256-tile GEMM (16x16x32), 8 waves, dbuf 128 KB LDS + coalesced epilogue ----------------
// R11 falsified the DBUF=0 co-residency theory (256-block grid = exactly 1 block/CU;
// nothing to co-schedule) and its quadrant epilogue cost ~8 us. R10 form restored.
template <int RELU, int OUT_BF16>
__global__ __launch_bounds__(512, 2)
void gemm256(const u16* __restrict__ A, const u16* __restrict__ Bt,
             const float* __restrict__ bias, void* __restrict__ Cout,
             int M, int N, int K) {
  __shared__ __align__(16) u16 smem[65536];  // 128 KB pool
  u16* As = smem;            // [2][256*64]  (64 KB)
  u16* Bs = smem + 32768;    // [2][256*64]  (64 KB)
  const int lane = threadIdx.x & 63, wid = threadIdx.x >> 6;  // 8 waves
  const int llo = lane & 15, lhi = lane >> 4;
  const int wr = wid >> 2, wc = wid & 3;   // 2M x 4N wave grid

  const int nwg = gridDim.x * gridDim.y;
  int lin = blockIdx.y * gridDim.x + blockIdx.x;
  if ((nwg & 7) == 0) lin = (lin & 7) * (nwg >> 3) + (lin >> 3);
  const int m0 = (lin / gridDim.x) * 256, n0 = (lin % gridDim.x) * 256;

  const int r8 = lane >> 3;
  const int c8 = ((lane & 7) ^ r8) * 8;   // XOR-swizzled source octet

  f4v acc[8][4];
  const f4v fz = {0.f, 0.f, 0.f, 0.f};
#pragma unroll
  for (int i = 0; i < 8; ++i)
#pragma unroll
    for (int j = 0; j < 4; ++j) acc[i][j] = fz;

  const u16* Ag = A  + (size_t)(m0 + r8) * K + c8;
  const u16* Bg = Bt + (size_t)(n0 + r8) * K + c8;
  const int nk = K >> 6;

  auto stage = [&](int buf, int kt) {
#pragma unroll
    for (int c = 0; c < 4; ++c) {
      int ch = wid * 4 + c;
      gl2lds16(Ag + (size_t)(ch * 8) * K + kt, As + buf * 16384 + ch * 512);
      gl2lds16(Bg + (size_t)(ch * 8) * K + kt, Bs + buf * 16384 + ch * 512);
    }
  };

  stage(0, 0);
  __syncthreads();  // tile 0 resident (vmcnt(0) drained)
  int cur = 0;
  for (int t = 0; t < nk; ++t) {
    if (t + 1 < nk) stage(cur ^ 1, (t + 1) * 64);  // prefetch BEFORE compute
#pragma unroll
    for (int ks = 0; ks < 2; ++ks) {
      const int so = ((ks * 4 + lhi) ^ (llo & 7)) * 8;  // swizzled read octet
      s8v b[4];
#pragma unroll
      for (int j = 0; j < 4; ++j)
        b[j] = *(const s8v*)&Bs[cur * 16384 + (wc * 64 + j * 16 + llo) * 64 + so];
#pragma unroll
      for (int i = 0; i < 8; ++i) {
        s8v a = *(const s8v*)&As[cur * 16384 + (wr * 128 + i * 16 + llo) * 64 + so];
#pragma unroll
        for (int j = 0; j < 4; ++j)
          acc[i][j] = __builtin_amdgcn_mfma_f32_16x16x32_bf16(a, b[j], acc[i][j], 0, 0, 0);
      }
    }
    __syncthreads();  // prefetch drain lands AFTER compute; safe buffer swap
    cur ^= 1;
  }

  if (OUT_BF16) {
    // stage C into own 16 KB LDS slice [128 rows][64 cols], XOR col-swizzle
    u16* ep = smem + wid * 8192;   // all waves past final barrier; own region only
#pragma unroll
    for (int j = 0; j < 4; ++j) {
      float bv = bias[n0 + wc * 64 + j * 16 + llo];
#pragma unroll
      for (int i = 0; i < 8; ++i) {
#pragma unroll
        for (int r = 0; r < 4; ++r) {
          int row = i * 16 + lhi * 4 + r;
          int col = j * 16 + llo;
          float v = acc[i][j][r] + bv;
          if (RELU) v = fmaxf(v, 0.0f);
          ep[row * 64 + (col ^ ((row & 7) * 8))] = f2bf(v);
        }
      }
    }
    // coalesced read-back + 16 B/lane stores (8 lanes = full 128 B line)
    const int c0 = (lane & 7) * 8;
#pragma unroll
    for (int p = 0; p < 16; ++p) {
      int row = p * 8 + (lane >> 3);
      s8v vv = *(const s8v*)&ep[row * 64 + (c0 ^ ((row & 7) * 8))];
      *(s8v*)((u16*)Cout + (size_t)(m0 + wr * 128 + row) * N + n0 + wc * 64 + c0) = vv;
    }
  } else {
    // fp32 path (unused currently): original per-element stores
#pragma unroll
    for (int j = 0; j < 4; ++j) {
      int col = n0 + wc * 64 + j * 16 + llo;
      float bv = bias[col];
#pragma unroll
      for (int i = 0; i < 8; ++i) {
        int r0 = m0 + wr * 128 + i * 16 + lhi * 4;
#pragma unroll
        for (int r = 0; r < 4; ++r) {
          size_t idx = (size_t)(r0 + r) * N + col;
          float v = acc[i][j][r] + bv;
          if (RELU) v = fmaxf(v, 0.0f);
          ((float*)Cout)[idx] = v;
        }
      }
    }
  }
}

// ---------------- flash attention, split-KV x2, IN-REGISTER softmax (R7 verified) ----------------
// + T5 setprio around MFMA clusters (R10 verified: part of the -7.5 us win)
__global__ __launch_bounds__(256, 3)
void flash_attn(const u16* __restrict__ QKV, u16* __restrict__ Pacc,
                float* __restrict__ Pml) {
  // LDS pool: Ks[128][64] swizzled octets (Q tile staged here first), Vt[64][136]
  __shared__ __align__(16) u16 smem[16896];
  u16* Ks = smem;          // [128][64]
  u16* Vt = smem + 8192;   // [64][136]

  const int tid = threadIdx.x;
  const int lane = tid & 63, wid = tid >> 6;
  const int llo = lane & 15, lhi = lane >> 4;
  int lin = blockIdx.y * 16 + blockIdx.x;       // 512 per z-slab, %8==0
  lin = (lin & 7) * 64 + (lin >> 3);            // bijective XCD swizzle
  const int qt = lin & 15, bh = lin >> 4, z = blockIdx.z;
  const int b = bh >> 4, h = bh & 15;
  const int LDM = QKVN;
  const size_t base = (size_t)b * SEQ * LDM + h * 64;
  const u16* Qb = QKV + base + (size_t)qt * 128 * LDM;          // Q cols [0,1024)
  const u16* Kb = QKV + base + 1024;                            // K cols
  const u16* Vb = QKV + base + 2048;                            // V cols
  const int r8 = lane >> 3;
  const int c8 = ((lane & 7) ^ r8) * 8;  // swizzled source octet

  // stage Q tile into Ks region (DMA, swizzled), pull to regs, then release
#pragma unroll
  for (int c = 0; c < 4; ++c) {
    int ch = wid * 4 + c;
    gl2lds16(Qb + (size_t)(ch * 8 + r8) * LDM + c8, Ks + ch * 512);
  }
  __syncthreads();
  s8v qf[2][2];
#pragma unroll
  for (int mb = 0; mb < 2; ++mb)
#pragma unroll
    for (int ks = 0; ks < 2; ++ks)
      qf[mb][ks] = *(const s8v*)&Ks[(wid * 32 + mb * 16 + llo) * 64 +
                                    (((ks * 4 + lhi) ^ (llo & 7)) * 8)];
  __syncthreads();  // all qf reads done before K staging overwrites

  f4v accO[2][4];
  float l_run[2] = {0.f, 0.f};  // per-lane partial row sums (this lane's 32 keys/tile)
  const f4v fz = {0.f, 0.f, 0.f, 0.f};
#pragma unroll
  for (int mb = 0; mb < 2; ++mb)
#pragma unroll
    for (int db = 0; db < 4; ++db) accO[mb][db] = fz;

  for (int kt = z * 8; kt < z * 8 + 8; ++kt) {
    // stage K (DMA, swizzled)
#pragma unroll
    for (int c = 0; c < 4; ++c) {
      int ch = wid * 4 + c;
      gl2lds16(Kb + (size_t)(kt * 128 + ch * 8 + r8) * LDM + c8, Ks + ch * 512);
    }
    // stage V transposed: wave-uniform d-octet, lane = key pair -> conflict-free b32 writes
#pragma unroll
    for (int it = 0; it < 2; ++it) {
      int o  = wid + it * 4;                  // d-octet, uniform per wave
      int k2 = lane * 2;                      // key pair
      const u16* vp = Vb + (size_t)(kt * 128 + k2) * LDM + o * 8;
      s8v v0 = *(const s8v*)vp;
      s8v v1 = *(const s8v*)(vp + LDM);
      const u16* e0 = (const u16*)&v0;
      const u16* e1 = (const u16*)&v1;
#pragma unroll
      for (int j = 0; j < 8; ++j) {
        unsigned pk = (unsigned)e0[j] | ((unsigned)e1[j] << 16);
        *(unsigned*)&Vt[(o * 8 + j) * 136 + k2] = pk;
      }
    }
    __syncthreads();

    // swapped QK^T per 32-key block + in-register softmax/pack
    s8v pa[2][4];  // [mb][ksb] PV A-fragments
#pragma unroll
    for (int ksb = 0; ksb < 4; ++ksb) {
      f4v sA[2], sB[2];  // score tiles nb=2*ksb, 2*ksb+1  (only 16 f32 live)
#pragma unroll
      for (int mb = 0; mb < 2; ++mb) { sA[mb] = fz; sB[mb] = fz; }
#pragma unroll
      for (int ks = 0; ks < 2; ++ks) {
        const int so = ((ks * 4 + lhi) ^ (llo & 7)) * 8;
        s8v kfA = *(const s8v*)&Ks[((ksb * 2 + 0) * 16 + llo) * 64 + so];
        s8v kfB = *(const s8v*)&Ks[((ksb * 2 + 1) * 16 + llo) * 64 + so];
        __builtin_amdgcn_s_setprio(1);
#pragma unroll
        for (int mb = 0; mb < 2; ++mb) {
          sA[mb] = __builtin_amdgcn_mfma_f32_16x16x32_bf16(kfA, qf[mb][ks], sA[mb], 0, 0, 0);
          sB[mb] = __builtin_amdgcn_mfma_f32_16x16x32_bf16(kfB, qf[mb][ks], sB[mb], 0, 0, 0);
        }
        __builtin_amdgcn_s_setprio(0);
      }
#pragma unroll
      for (int mb = 0; mb < 2; ++mb) {
        float pA0 = __builtin_amdgcn_exp2f(sA[mb][0]);
        float pA1 = __builtin_amdgcn_exp2f(sA[mb][1]);
        float pA2 = __builtin_amdgcn_exp2f(sA[mb][2]);
        float pA3 = __builtin_amdgcn_exp2f(sA[mb][3]);
        float pB0 = __builtin_amdgcn_exp2f(sB[mb][0]);
        float pB1 = __builtin_amdgcn_exp2f(sB[mb][1]);
        float pB2 = __builtin_amdgcn_exp2f(sB[mb][2]);
        float pB3 = __builtin_amdgcn_exp2f(sB[mb][3]);
        l_run[mb] += ((pA0 + pA1) + (pA2 + pA3)) + ((pB0 + pB1) + (pB2 + pB3));
        // pack to bf16 pairs: a* = tile 2ksb (keys 4*lhi+{0..3}), b* = tile 2ksb+1
        unsigned a0 = cvt_pk_bf16(pA0, pA1), a1 = cvt_pk_bf16(pA2, pA3);
        unsigned b0 = cvt_pk_bf16(pB0, pB1), b1 = cvt_pk_bf16(pB2, pB3);
        // redistribute across lhi groups into A-fragment words:
        // after p32+p16: a0 -> word0 (keys 8lhi+0,1), b0 -> word2 (8lhi+4,5)
        //               a1 -> word1 (keys 8lhi+2,3), b1 -> word3 (8lhi+6,7)
        pl32swap(a0, b0); pl16swap(a0, b0);
        pl32swap(a1, b1); pl16swap(a1, b1);
        union { unsigned u[4]; s8v v; } pk;
        pk.u[0] = a0; pk.u[1] = a1; pk.u[2] = b0; pk.u[3] = b1;
        pa[mb][ksb] = pk.v;
      }
    }

    // O += P @ V
#pragma unroll
    for (int ks = 0; ks < 4; ++ks) {
      s8v vb2[4];
#pragma unroll
      for (int db = 0; db < 4; ++db)
        vb2[db] = *(const s8v*)&Vt[(db * 16 + llo) * 136 + ks * 32 + lhi * 8];
      __builtin_amdgcn_s_setprio(1);
#pragma unroll
      for (int mb = 0; mb < 2; ++mb)
#pragma unroll
        for (int db = 0; db < 4; ++db)
          accO[mb][db] = __builtin_amdgcn_mfma_f32_16x16x32_bf16(pa[mb][ks], vb2[db], accO[mb][db], 0, 0, 0);
      __builtin_amdgcn_s_setprio(0);
    }
    __syncthreads();  // before next stage overwrites Ks/Vt
  }

  // epilogue: reduce l across the 4 lhi key-groups, write bf16 partial acc + fp32 l
#pragma unroll
  for (int mb = 0; mb < 2; ++mb) {
    l_run[mb] += __shfl_xor(l_run[mb], 16, 64);
    l_run[mb] += __shfl_xor(l_run[mb], 32, 64);
  }
#pragma unroll
  for (int mb = 0; mb < 2; ++mb) {
    int row0 = qt * 128 + wid * 32 + mb * 16;
    size_t ibase = (size_t)(z * 32 + bh) * SEQ + row0;
    if (lane < 16) Pml[ibase + lane] = l_run[mb];   // lhi==0 lanes, query=row0+llo
#pragma unroll
    for (int r = 0; r < 4; ++r) {
      size_t irow = ibase + lhi * 4 + r;
#pragma unroll
      for (int db = 0; db < 4; ++db)
        Pacc[irow * 64 + db * 16 + llo] = f2bf(accO[mb][db][r]);
    }
  }
}

// ---------------- combine the two KV splits -> ctx (bf16 [tok][1024]), 16 B/thread ----------------
__global__ __launch_bounds__(256)
void attn_combine(const u16* __restrict__ Pacc, const float* __restrict__ Pml,
                  u16* __restrict__ ctx) {
  int g = blockIdx.x * 256 + threadIdx.x;  // oct id; 32*2048*8 total
  int d8 = g & 7;                          // octet of d (8 values, 16 B)
  int row = (g >> 3) & (SEQ - 1);
  int bh = g >> 14;
  int b = bh >> 4, h = bh & 15;
  size_t i0 = (size_t)bh * SEQ + row;
  size_t i1 = (size_t)(32 + bh) * SEQ + row;
  float inv = 1.0f / (Pml[i0] + Pml[i1]);
  uint4 pa = ((const uint4*)Pacc)[i0 * 8 + d8];
  uint4 pb = ((const uint4*)Pacc)[i1 * 8 + d8];
  uint4 o;
  {
    float lo = u2f(pa.x << 16) + u2f(pb.x << 16);
    float hi = u2f(pa.x & 0xffff0000u) + u2f(pb.x & 0xffff0000u);
    o.x = (unsigned)f2bf(lo * inv) | ((unsigned)f2bf(hi * inv) << 16);
  }
  {
    float lo = u2f(pa.y << 16) + u2f(pb.y << 16);
    float hi = u2f(pa.y & 0xffff0000u) + u2f(pb.y & 0xffff0000u);
    o.y = (unsigned)f2bf(lo * inv) | ((unsigned)f2bf(hi * inv) << 16);
  }
  {
    float lo = u2f(pa.z << 16) + u2f(pb.z << 16);
    float hi = u2f(pa.z & 0xffff0000u) + u2f(pb.z & 0xffff0000u);
    o.z = (unsigned)f2bf(lo * inv) | ((unsigned)f2bf(hi * inv) << 16);
  }
  {
    float lo = u2f(pa.w << 16) + u2f(pb.w << 16);
    float hi = u2f(pa.w & 0xffff0000u) + u2f(pb.w & 0xffff0000u);
    o.w = (unsigned)f2bf(lo * inv) | ((unsigned)f2bf(hi * inv) << 16);
  }
  ((uint4*)ctx)[(size_t)(b * SEQ + row) * (DMODEL / 8) + h * 8 + d8] = o;
}

// ---------------- orchestration ----------------
extern "C" void kernel_launch(void* const* d_in, const int* in_sizes, int n_in,
                              void* d_out, int out_size, void* d_ws, size_t ws_size,
                              hipStream_t stream) {
  const float* x   = (const float*)d_in[0];
  const float* Wq  = (const float*)d_in[1];  const float* bq = (const float*)d_in[2];
  const float* Wk  = (const float*)d_in[3];  const float* bk = (const float*)d_in[4];
  const float* Wv  = (const float*)d_in[5];  const float* bv = (const float*)d_in[6];
  const float* Wo  = (const float*)d_in[7];  const float* bo = (const float*)d_in[8];
  const float* W1  = (const float*)d_in[9];  const float* b1 = (const float*)d_in[10];
  const float* W2  = (const float*)d_in[11]; const float* b2 = (const float*)d_in[12];
  const float* l1a = (const float*)d_in[13]; const float* l1b = (const float*)d_in[14];
  const float* l2a = (const float*)d_in[15]; const float* l2b = (const float*)d_in[16];

  char* ws = (char*)d_ws;
  const size_t MB = 1u << 20;
  // weights 0-25 MB
  u16*   wqkv_t = (u16*)(ws + 0);          // [3072][1024] bf16: 6 MB
  u16*   wo_t   = (u16*)(ws + 6 * MB);     // [1024][1024]: 2 MB
  u16*   w1_t   = (u16*)(ws + 8 * MB);     // [4096][1024]: 8 MB
  u16*   w2_t   = (u16*)(ws + 16 * MB);    // [1024][4096]: 8 MB
  float* bqkv   = (float*)(ws + 24 * MB);  // 3072 floats
  // activations (time-multiplexed; max 97.5 MB — proven-safe footprint)
  u16*   xn1    = (u16*)(ws + 25 * MB);    // [4096][1024] bf16: 8 MB (ln1 -> QKV)
  u16*   qkv    = (u16*)(ws + 33 * MB);    // [4096][3072] bf16: 24 MB (QKV -> flash)
  u16*   Pacc   = (u16*)(ws + 57 * MB);    // [2][32][2048][64] bf16: 16 MB (flash -> combine)
  float* Pml    = (float*)(ws + 73 * MB);  // [2][32][2048] fp32: 0.5 MB
  u16*   ctx    = (u16*)(ws + 73 * MB + MB / 2);  // [4096][1024] bf16: 8 MB (combine -> O-proj)
  float* hgm    = (float*)(ws + 57 * MB);  // h fp32 16 MB (O-proj z0 direct; Pacc dead)
  float* po1    = (float*)(ws + 25 * MB);  // O-proj z1 partial fp32 16 MB (xn1+qkv dead)
  u16*   n2     = (u16*)(ws + 73 * MB + MB / 2);  // LN2 out 8 MB (ctx dead after O-proj)
  u16*   mid    = (u16*)(ws + 25 * MB);    // [4096][4096] bf16 32 MB (po1 dead)
  float* pf     = (float*)(ws + 73 * MB + MB / 2);  // FFN2 z1 partial 16 MB (n2/Pml dead)

  dim3 blk(256);

  // fused weight transposes + bias concat (Wq/bq pre-scaled by log2e for exp2-domain softmax)
  prep<<<dim3(12300), blk, 0, stream>>>(Wq, Wk, Wv, Wo, W1, W2, bq, bk, bv,
                                        wqkv_t, wo_t, w1_t, w2_t, bqkv);

  // LN1
  ln_bf16<<<NTOK, blk, 0, stream>>>(x, xn1, l1a, l1b);

  // fused QKV projection: [4096,1024] x [1024,3072] -> [4096,3072]  (256-tile, 192 blocks)
  gemm256<0, 1><<<dim3(12, 16), dim3(512), 0, stream>>>(xn1, wqkv_t, bqkv, qkv,
                                                        NTOK, QKVN, DMODEL);

  // attention, split-KV x2 -> bf16 partials, then combine
  flash_attn<<<dim3(16, 32, 2), blk, 0, stream>>>(qkv, Pacc, Pml);
  attn_combine<<<dim3(2048), blk, 0, stream>>>(Pacc, Pml, ctx);

  // O projection + residual, split-K x2 WITHOUT atomics:
  // z0 -> hgm = ctx@Wo(K-half0) + bo + x ; z1 -> po1 = ctx@Wo(K-half1)
  gemm_bt<0, 1, 0, 1><<<dim3(8, 32, 2), blk, 0, stream>>>(ctx, wo_t, bo, x, hgm, po1,
                                                          NTOK, DMODEL, DMODEL);

  // fused: h = hgm + po1 (in place, one ordered add -> deterministic); n2 = LN2(h)
  ln2_comb<<<NTOK, blk, 0, stream>>>(hgm, po1, n2, l2a, l2b);

  // FFN1: relu(n2 @ W1 + b1) -> bf16  (256-tile, 256 blocks = perfect fill; DBUF form)
  gemm256<1, 1><<<dim3(16, 16), dim3(512), 0, stream>>>(n2, w1_t, b1, mid,
                                                        NTOK, DFF, DMODEL);

  // FFN2 split-K x2 WITHOUT atomics: z0 -> d_out = mid@W2(half0) + b2 + h ; z1 -> pf
  gemm_bt<0, 1, 0, 1><<<dim3(8, 32, 2), blk, 0, stream>>>(mid, w2_t, b2, hgm,
                                                          (float*)d_out, pf,
                                                          NTOK, DMODEL, DFF);

  // d_out += pf  (single ordered add per element -> bitwise deterministic)
  add2<<<dim3(4096), blk, 0, stream>>>((float*)d_out, pf);
}

// Round 13
// 341.354 us; speedup vs baseline: 1.0216x; 1.0199x over previous
//
#include <hip/hip_runtime.h>

#define DMODEL 1024
#define DFF    4096
#define SEQ    2048
#define NTOK   4096   // B*S = 2*2048
#define QKVN   3072   // fused QKV output width
#define LOG2E  1.4426950408889634f

typedef unsigned short u16;
typedef short s8v __attribute__((ext_vector_type(8)));
typedef float f4v __attribute__((ext_vector_type(4)));

__device__ __forceinline__ u16 f2bf(float f) {
  union { float f; unsigned u; } c; c.f = f;
  unsigned r = c.u + 0x7fffu + ((c.u >> 16) & 1u);
  return (u16)(r >> 16);
}
__device__ __forceinline__ float u2f(unsigned u) {
  union { unsigned u; float f; } c; c.u = u; return c.f;
}

// v_cvt_pk_bf16_f32: dst.lo = bf16(lo), dst.hi = bf16(hi)  (RNE)
__device__ __forceinline__ unsigned cvt_pk_bf16(float lo, float hi) {
  unsigned r;
  asm("v_cvt_pk_bf16_f32 %0, %1, %2" : "=v"(r) : "v"(lo), "v"(hi));
  return r;
}
__device__ __forceinline__ void pl32swap(unsigned& x, unsigned& y) {
  asm("v_permlane32_swap_b32 %0, %1" : "+v"(x), "+v"(y));
}
__device__ __forceinline__ void pl16swap(unsigned& x, unsigned& y) {
  asm("v_permlane16_swap_b32 %0, %1" : "+v"(x), "+v"(y));
}

typedef const __attribute__((address_space(1))) unsigned GAS;
typedef __attribute__((address_space(3))) unsigned LAS;
__device__ __forceinline__ void gl2lds16(const void* g, void* l) {
  __builtin_amdgcn_global_load_lds((GAS*)g, (LAS*)l, 16, 0, 0);
}

// ---------------- fused prep: 6 weight transposes (fp32->bf16, optional scale) + QKV bias concat ----------------
// 64x32 tiles: each transposed output row = 64 contiguous u16 = 128 B = ONE full
// cache line (32 lanes x packed u32) -> no partial-line write amplification
// (same mechanism as the verified FFN1 epilogue fix, R7). LDS stride 33 (odd);
// store-read is 2-way conflicted only (free, m136).
__device__ __forceinline__ void tr64(const float* __restrict__ W, u16* __restrict__ Wt,
                                     int K, int N, int bx, int by, float (*sh)[33],
                                     float scale) {
  int n0 = bx * 32, k0 = by * 64;
  int tx = threadIdx.x & 31, ty = threadIdx.x >> 5;
#pragma unroll
  for (int r = ty; r < 64; r += 8) sh[r][tx] = W[(size_t)(k0 + r) * N + n0 + tx];
  __syncthreads();
#pragma unroll
  for (int r = ty; r < 32; r += 8) {
    unsigned v = (unsigned)f2bf(sh[2 * tx][r] * scale) |
                 ((unsigned)f2bf(sh[2 * tx + 1][r] * scale) << 16);
    *(unsigned*)&Wt[(size_t)(n0 + r) * K + k0 + 2 * tx] = v;
  }
}

__global__ __launch_bounds__(256)
void prep(const float* __restrict__ Wq, const float* __restrict__ Wk,
          const float* __restrict__ Wv, const float* __restrict__ Wo,
          const float* __restrict__ W1, const float* __restrict__ W2,
          const float* __restrict__ bq, const float* __restrict__ bk,
          const float* __restrict__ bv,
          u16* __restrict__ wqkv_t, u16* __restrict__ wo_t,
          u16* __restrict__ w1_t, u16* __restrict__ w2_t, float* __restrict__ bqkv) {
  __shared__ float sh[64][33];
  int b = blockIdx.x;
  if (b < 512) {
    // Wq scaled by log2(e): softmax runs in exp2 domain (scores = 1.4427 * q.k)
    tr64(Wq, wqkv_t, 1024, 1024, b & 31, b >> 5, sh, LOG2E);            // 16x32 tiles
  } else if (b < 1024) {
    b -= 512;  tr64(Wk, wqkv_t + (1u << 20), 1024, 1024, b & 31, b >> 5, sh, 1.0f);
  } else if (b < 1536) {
    b -= 1024; tr64(Wv, wqkv_t + (2u << 20), 1024, 1024, b & 31, b >> 5, sh, 1.0f);
  } else if (b < 2048) {
    b -= 1536; tr64(Wo, wo_t, 1024, 1024, b & 31, b >> 5, sh, 1.0f);
  } else if (b < 4096) {
    b -= 2048; tr64(W1, w1_t, 1024, 4096, b & 127, b >> 7, sh, 1.0f);   // K=1024,N=4096: 16x128
  } else if (b < 6144) {
    b -= 4096; tr64(W2, w2_t, 4096, 1024, b & 31, b >> 5, sh, 1.0f);    // K=4096,N=1024: 64x32
  } else {
    int t = (b - 6144) * 256 + threadIdx.x;  // 0..3071
    float v = (t < 1024) ? bq[t] * LOG2E : (t < 2048 ? bk[t - 1024] : bv[t - 2048]);
    bqkv[t] = v;
  }
}

// ---------------- LayerNorm (ddof=1, alpha/(std+eps), scalar alpha/beta) -> bf16 ----------------
__global__ __launch_bounds__(256)
void ln_bf16(const float* __restrict__ X, u16* __restrict__ Y,
             const float* __restrict__ a_p, const float* __restrict__ b_p) {
  int row = blockIdx.x;
  const float4* xr = (const float4*)(X + (size_t)row * DMODEL);
  float4 v = xr[threadIdx.x];
  float s  = v.x + v.y + v.z + v.w;
  float ss = v.x * v.x + v.y * v.y + v.z * v.z + v.w * v.w;
#pragma unroll
  for (int m = 32; m >= 1; m >>= 1) { s += __shfl_xor(s, m, 64); ss += __shfl_xor(ss, m, 64); }
  __shared__ float red[8];
  int wid = threadIdx.x >> 6, lane = threadIdx.x & 63;
  if (lane == 0) { red[wid] = s; red[4 + wid] = ss; }
  __syncthreads();
  s  = red[0] + red[1] + red[2] + red[3];
  ss = red[4] + red[5] + red[6] + red[7];
  float mean = s * (1.0f / 1024.0f);
  float var  = fmaxf((ss - s * mean) * (1.0f / 1023.0f), 0.0f);
  float k    = a_p[0] / (sqrtf(var) + 1e-6f);
  float beta = b_p[0];
  ushort4 o;
  o.x = f2bf((v.x - mean) * k + beta);
  o.y = f2bf((v.y - mean) * k + beta);
  o.z = f2bf((v.z - mean) * k + beta);
  o.w = f2bf((v.w - mean) * k + beta);
  ((ushort4*)(Y + (size_t)row * DMODEL))[threadIdx.x] = o;
}

// ---------------- fused: h += po1 (in place); n2 = LN2(h) ----------------
__global__ __launch_bounds__(256)
void ln2_comb(float* __restrict__ H, const float* __restrict__ P1,
              u16* __restrict__ Y, const float* __restrict__ a_p,
              const float* __restrict__ b_p) {
  int row = blockIdx.x;
  float4* hr = (float4*)(H + (size_t)row * DMODEL);
  float4 v = hr[threadIdx.x];
  float4 p = ((const float4*)(P1 + (size_t)row * DMODEL))[threadIdx.x];
  v.x += p.x; v.y += p.y; v.z += p.z; v.w += p.w;
  hr[threadIdx.x] = v;   // materialize h for FFN2 residual
  float s  = v.x + v.y + v.z + v.w;
  float ss = v.x * v.x + v.y * v.y + v.z * v.z + v.w * v.w;
#pragma unroll
  for (int m = 32; m >= 1; m >>= 1) { s += __shfl_xor(s, m, 64); ss += __shfl_xor(ss, m, 64); }
  __shared__ float red[8];
  int wid = threadIdx.x >> 6, lane = threadIdx.x & 63;
  if (lane == 0) { red[wid] = s; red[4 + wid] = ss; }
  __syncthreads();
  s  = red[0] + red[1] + red[2] + red[3];
  ss = red[4] + red[5] + red[6] + red[7];
  float mean = s * (1.0f / 1024.0f);
  float var  = fmaxf((ss - s * mean) * (1.0f / 1023.0f), 0.0f);
  float k    = a_p[0] / (sqrtf(var) + 1e-6f);
  float beta = b_p[0];
  ushort4 o;
  o.x = f2bf((v.x - mean) * k + beta);
  o.y = f2bf((v.y - mean) * k + beta);
  o.z = f2bf((v.z - mean) * k + beta);
  o.w = f2bf((v.w - mean) * k + beta);
  ((ushort4*)(Y + (size_t)row * DMODEL))[threadIdx.x] = o;
}

// ---------------- d_out += pf (FFN2 split-K combine; one ordered add -> deterministic) ----------------
__global__ __launch_bounds__(256)
void add2(float* __restrict__ D, const float* __restrict__ P) {
  size_t g = (size_t)blockIdx.x * 256 + threadIdx.x;
  float4 a = ((float4*)D)[g];
  float4 b = ((const float4*)P)[g];
  a.x += b.x; a.y += b.y; a.z += b.z; a.w += b.w;
  ((float4*)D)[g] = a;
}

// ---------------- 128-tile GEMM (16x16x32), single-buffer, 3 blocks/CU + XCD swizzle ----------------
// SPLIT=1: split-K over gridDim.z WITHOUT atomics: z0 writes v+bias(+resid) directly
// to Cout; z1 writes raw v to Cpart. Downstream does ONE ordered add -> deterministic.
template <int RELU, int RESID, int OUT_BF16, int SPLIT>
__global__ __launch_bounds__(256, 3)
void gemm_bt(const u16* __restrict__ A, const u16* __restrict__ Bt,
             const float* __restrict__ bias, const float* __restrict__ resid,
             void* __restrict__ Cout, float* __restrict__ Cpart,
             int M, int N, int K) {
  __shared__ __align__(16) u16 As[128 * 64];
  __shared__ __align__(16) u16 Bs[128 * 64];
  const int lane = threadIdx.x & 63, wid = threadIdx.x >> 6;
  const int llo = lane & 15, lhi = lane >> 4;

  // XCD-aware tile swizzle (proven: FETCH 143->57 MB in R2)
  const int nwg = gridDim.x * gridDim.y;
  int lin = blockIdx.y * gridDim.x + blockIdx.x;
  if ((nwg & 7) == 0) lin = (lin & 7) * (nwg >> 3) + (lin >> 3);
  const int m0 = (lin / gridDim.x) * 128, n0 = (lin % gridDim.x) * 128;

  const int wm = wid & 1, wn = wid >> 1;
  const int r8 = lane >> 3;
  const int c8 = ((lane & 7) ^ r8) * 8;   // XOR-swizzled source octet for this lane's LDS slot

  f4v acc[4][4];
  const f4v fz = {0.f, 0.f, 0.f, 0.f};
#pragma unroll
  for (int i = 0; i < 4; ++i)
#pragma unroll
    for (int j = 0; j < 4; ++j) acc[i][j] = fz;

  const u16* Ag = A  + (size_t)(m0 + r8) * K + c8;
  const u16* Bg = Bt + (size_t)(n0 + r8) * K + c8;

  const int Kp = SPLIT ? (K / gridDim.z) : K;
  const int kbeg = SPLIT ? blockIdx.z * Kp : 0;
  const int kend = kbeg + Kp;

  for (int kt = kbeg; kt < kend; kt += 64) {
#pragma unroll
    for (int c = 0; c < 4; ++c) {
      int ch = wid * 4 + c;
      gl2lds16(Ag + (size_t)(ch * 8) * K + kt, As + ch * 512);
      gl2lds16(Bg + (size_t)(ch * 8) * K + kt, Bs + ch * 512);
    }
    __syncthreads();
#pragma unroll
    for (int ks = 0; ks < 2; ++ks) {
      const int so = ((ks * 4 + lhi) ^ (llo & 7)) * 8;  // swizzled read octet
      s8v a[4], b[4];
#pragma unroll
      for (int i = 0; i < 4; ++i)
        a[i] = *(const s8v*)&As[(wm * 64 + i * 16 + llo) * 64 + so];
#pragma unroll
      for (int j = 0; j < 4; ++j)
        b[j] = *(const s8v*)&Bs[(wn * 64 + j * 16 + llo) * 64 + so];
#pragma unroll
      for (int i = 0; i < 4; ++i)
#pragma unroll
        for (int j = 0; j < 4; ++j)
          acc[i][j] = __builtin_amdgcn_mfma_f32_16x16x32_bf16(a[i], b[j], acc[i][j], 0, 0, 0);
    }
    __syncthreads();
  }
  // epilogue: C layout col=lane&15, row=(lane>>4)*4+r
#pragma unroll
  for (int j = 0; j < 4; ++j) {
    int col = n0 + wn * 64 + j * 16 + llo;
    float bv = bias[col];
#pragma unroll
    for (int i = 0; i < 4; ++i) {
      int r0 = m0 + wm * 64 + i * 16 + lhi * 4;
#pragma unroll
      for (int r = 0; r < 4; ++r) {
        size_t idx = (size_t)(r0 + r) * N + col;
        float v = acc[i][j][r];
        if (SPLIT) {
          if (blockIdx.z == 0) {
            v += bv;
            if (RESID) v += resid[idx];
            ((float*)Cout)[idx] = v;   // plain store, no RMW
          } else {
            Cpart[idx] = v;            // raw partial
          }
        } else {
          v += bv;
          if (RESID) v += resid[idx];
          if (RELU) v = fmaxf(v, 0.0f);
          if (OUT_BF16) ((u16*)Cout)[idx] = f2bf(v);
          else          ((float*)Cout)[idx] = v;
        }
      }
    }
  }
}

// ---------------- 256-tile GEMM (16x16x32), 8 waves, dbuf 128 KB LDS + coalesced epilogue ----------------
template <int RELU, int OUT_BF16>
__global__ __launch_bounds__(512, 2)
void gemm256(const u16* __restrict__ A, const u16* __restrict__ Bt,
             const float* __restrict__ bias, void* __restrict__ Cout,
             int M, int N, int K) {
  __shared__ __align__(16) u16 smem[65536];  // 128 KB pool
  u16* As = smem;            // [2][256*64]  (64 KB)
  u16* Bs = smem + 32768;    // [2][256*64]  (64 KB)
  const int lane = threadIdx.x & 63, wid = threadIdx.x >> 6;  // 8 waves
  const int llo = lane & 15, lhi = lane >> 4;
  const int wr = wid >> 2, wc = wid & 3;   // 2M x 4N wave grid

  const int nwg = gridDim.x * gridDim.y;
  int lin = blockIdx.y * gridDim.x + blockIdx.x;
  if ((nwg & 7) == 0) lin = (lin & 7) * (nwg >> 3) + (lin >> 3);
  const int m0 = (lin / gridDim.x) * 256, n0 = (lin % gridDim.x) * 256;

  const int r8 = lane >> 3;
  const int c8 = ((lane & 7) ^ r8) * 8;   // XOR-swizzled source octet

  f4v acc[8][4];
  const f4v fz = {0.f, 0.f, 0.f, 0.f};
#pragma unroll
  for (int i = 0; i < 8; ++i)
#pragma unroll
    for (int j = 0; j < 4; ++j) acc[i][j] = fz;

  const u16* Ag = A  + (size_t)(m0 + r8) * K + c8;
  const u16* Bg = Bt + (size_t)(n0 + r8) * K + c8;
  const int nk = K >> 6;

  auto stage = [&](int buf, int kt) {
#pragma unroll
    for (int c = 0; c < 4; ++c) {
      int ch = wid * 4 + c;
      gl2lds16(Ag + (size_t)(ch * 8) * K + kt, As + buf * 16384 + ch * 512);
      gl2lds16(Bg + (size_t)(ch * 8) * K + kt, Bs + buf * 16384 + ch * 512);
    }
  };

  stage(0, 0);
  __syncthreads();  // tile 0 resident (vmcnt(0) drained)
  int cur = 0;
  for (int t = 0; t < nk; ++t) {
    if (t + 1 < nk) stage(cur ^ 1, (t + 1) * 64);  // prefetch BEFORE compute
#pragma unroll
    for (int ks = 0; ks < 2; ++ks) {
      const int so = ((ks * 4 + lhi) ^ (llo & 7)) * 8;  // swizzled read octet
      s8v b[4];
#pragma unroll
      for (int j = 0; j < 4; ++j)
        b[j] = *(const s8v*)&Bs[cur * 16384 + (wc * 64 + j * 16 + llo) * 64 + so];
#pragma unroll
      for (int i = 0; i < 8; ++i) {
        s8v a = *(const s8v*)&As[cur * 16384 + (wr * 128 + i * 16 + llo) * 64 + so];
#pragma unroll
        for (int j = 0; j < 4; ++j)
          acc[i][j] = __builtin_amdgcn_mfma_f32_16x16x32_bf16(a, b[j], acc[i][j], 0, 0, 0);
      }
    }
    __syncthreads();  // prefetch drain lands AFTER compute; safe buffer swap
    cur ^= 1;
  }

  if (OUT_BF16) {
    // stage C into own 16 KB LDS slice [128 rows][64 cols], XOR col-swizzle
    u16* ep = smem + wid * 8192;   // all waves past final barrier; own region only
#pragma unroll
    for (int j = 0; j < 4; ++j) {
      float bv = bias[n0 + wc * 64 + j * 16 + llo];
#pragma unroll
      for (int i = 0; i < 8; ++i) {
#pragma unroll
        for (int r = 0; r < 4; ++r) {
          int row = i * 16 + lhi * 4 + r;
          int col = j * 16 + llo;
          float v = acc[i][j][r] + bv;
          if (RELU) v = fmaxf(v, 0.0f);
          ep[row * 64 + (col ^ ((row & 7) * 8))] = f2bf(v);
        }
      }
    }
    // coalesced read-back + 16 B/lane stores (8 lanes = full 128 B line)
    const int c0 = (lane & 7) * 8;
#pragma unroll
    for (int p = 0; p < 16; ++p) {
      int row = p * 8 + (lane >> 3);
      s8v vv = *(const s8v*)&ep[row * 64 + (c0 ^ ((row & 7) * 8))];
      *(s8v*)((u16*)Cout + (size_t)(m0 + wr * 128 + row) * N + n0 + wc * 64 + c0) = vv;
    }
  } else {
    // fp32 path (unused currently): original per-element stores
#pragma unroll
    for (int j = 0; j < 4; ++j) {
      int col = n0 + wc * 64 + j * 16 + llo;
      float bv = bias[col];
#pragma unroll
      for (int i = 0; i < 8; ++i) {
        int r0 = m0 + wr * 128 + i * 16 + lhi * 4;
#pragma unroll
        for (int r = 0; r < 4; ++r) {
          size_t idx = (size_t)(r0 + r) * N + col;
          float v = acc[i][j][r] + bv;
          if (RELU) v = fmaxf(v, 0.0f);
          ((float*)Cout)[idx] = v;
        }
      }
    }
  }
}

// ---------------- flash attention, split-KV x2, IN-REGISTER softmax (R7 verified) ----------------
// + T5 setprio around MFMA clusters (R10 verified: part of the -7.5 us win)
__global__ __launch_bounds__(256, 3)
void flash_attn(const u16* __restrict__ QKV, u16* __restrict__ Pacc,
                float* __restrict__ Pml) {
  // LDS pool: Ks[128][64] swizzled octets (Q tile staged here first), Vt[64][136]
  __shared__ __align__(16) u16 smem[16896];
  u16* Ks = smem;          // [128][64]
  u16* Vt = smem + 8192;   // [64][136]

  const int tid = threadIdx.x;
  const int lane = tid & 63, wid = tid >> 6;
  const int llo = lane & 15, lhi = lane >> 4;
  int lin = blockIdx.y * 16 + blockIdx.x;       // 512 per z-slab, %8==0
  lin = (lin & 7) * 64 + (lin >> 3);            // bijective XCD swizzle
  const int qt = lin & 15, bh = lin >> 4, z = blockIdx.z;
  const int b = bh >> 4, h = bh & 15;
  const int LDM = QKVN;
  const size_t base = (size_t)b * SEQ * LDM + h * 64;
  const u16* Qb = QKV + base + (size_t)qt * 128 * LDM;          // Q cols [0,1024)
  const u16* Kb = QKV + base + 1024;                            // K cols
  const u16* Vb = QKV + base + 2048;                            // V cols
  const int r8 = lane >> 3;
  const int c8 = ((lane & 7) ^ r8) * 8;  // swizzled source octet

  // stage Q tile into Ks region (DMA, swizzled), pull to regs, then release
#pragma unroll
  for (int c = 0; c < 4; ++c) {
    int ch = wid * 4 + c;
    gl2lds16(Qb + (size_t)(ch * 8 + r8) * LDM + c8, Ks + ch * 512);
  }
  __syncthreads();
  s8v qf[2][2];
#pragma unroll
  for (int mb = 0; mb < 2; ++mb)
#pragma unroll
    for (int ks = 0; ks < 2; ++ks)
      qf[mb][ks] = *(const s8v*)&Ks[(wid * 32 + mb * 16 + llo) * 64 +
                                    (((ks * 4 + lhi) ^ (llo & 7)) * 8)];
  __syncthreads();  // all qf reads done before K staging overwrites

  f4v accO[2][4];
  float l_run[2] = {0.f, 0.f};  // per-lane partial row sums (this lane's 32 keys/tile)
  const f4v fz = {0.f, 0.f, 0.f, 0.f};
#pragma unroll
  for (int mb = 0; mb < 2; ++mb)
#pragma unroll
    for (int db = 0; db < 4; ++db) accO[mb][db] = fz;

  for (int kt = z * 8; kt < z * 8 + 8; ++kt) {
    // stage K (DMA, swizzled)
#pragma unroll
    for (int c = 0; c < 4; ++c) {
      int ch = wid * 4 + c;
      gl2lds16(Kb + (size_t)(kt * 128 + ch * 8 + r8) * LDM + c8, Ks + ch * 512);
    }
    // stage V transposed: wave-uniform d-octet, lane = key pair -> conflict-free b32 writes
#pragma unroll
    for (int it = 0; it < 2; ++it) {
      int o  = wid + it * 4;                  // d-octet, uniform per wave
      int k2 = lane * 2;                      // key pair
      const u16* vp = Vb + (size_t)(kt * 128 + k2) * LDM + o * 8;
      s8v v0 = *(const s8v*)vp;
      s8v v1 = *(const s8v*)(vp + LDM);
      const u16* e0 = (const u16*)&v0;
      const u16* e1 = (const u16*)&v1;
#pragma unroll
      for (int j = 0; j < 8; ++j) {
        unsigned pk = (unsigned)e0[j] | ((unsigned)e1[j] << 16);
        *(unsigned*)&Vt[(o * 8 + j) * 136 + k2] = pk;
      }
    }
    __syncthreads();

    // swapped QK^T per 32-key block + in-register softmax/pack
    s8v pa[2][4];  // [mb][ksb] PV A-fragments
#pragma unroll
    for (int ksb = 0; ksb < 4; ++ksb) {
      f4v sA[2], sB[2];  // score tiles nb=2*ksb, 2*ksb+1  (only 16 f32 live)
#pragma unroll
      for (int mb = 0; mb < 2; ++mb) { sA[mb] = fz; sB[mb] = fz; }
#pragma unroll
      for (int ks = 0; ks < 2; ++ks) {
        const int so = ((ks * 4 + lhi) ^ (llo & 7)) * 8;
        s8v kfA = *(const s8v*)&Ks[((ksb * 2 + 0) * 16 + llo) * 64 + so];
        s8v kfB = *(const s8v*)&Ks[((ksb * 2 + 1) * 16 + llo) * 64 + so];
        __builtin_amdgcn_s_setprio(1);
#pragma unroll
        for (int mb = 0; mb < 2; ++mb) {
          sA[mb] = __builtin_amdgcn_mfma_f32_16x16x32_bf16(kfA, qf[mb][ks], sA[mb], 0, 0, 0);
          sB[mb] = __builtin_amdgcn_mfma_f32_16x16x32_bf16(kfB, qf[mb][ks], sB[mb], 0, 0, 0);
        }
        __builtin_amdgcn_s_setprio(0);
      }
#pragma unroll
      for (int mb = 0; mb < 2; ++mb) {
        float pA0 = __builtin_amdgcn_exp2f(sA[mb][0]);
        float pA1 = __builtin_amdgcn_exp2f(sA[mb][1]);
        float pA2 = __builtin_amdgcn_exp2f(sA[mb][2]);
        float pA3 = __builtin_amdgcn_exp2f(sA[mb][3]);
        float pB0 = __builtin_amdgcn_exp2f(sB[mb][0]);
        float pB1 = __builtin_amdgcn_exp2f(sB[mb][1]);
        float pB2 = __builtin_amdgcn_exp2f(sB[mb][2]);
        float pB3 = __builtin_amdgcn_exp2f(sB[mb][3]);
        l_run[mb] += ((pA0 + pA1) + (pA2 + pA3)) + ((pB0 + pB1) + (pB2 + pB3));
        // pack to bf16 pairs: a* = tile 2ksb (keys 4*lhi+{0..3}), b* = tile 2ksb+1
        unsigned a0 = cvt_pk_bf16(pA0, pA1), a1 = cvt_pk_bf16(pA2, pA3);
        unsigned b0 = cvt_pk_bf16(pB0, pB1), b1 = cvt_pk_bf16(pB2, pB3);
        // redistribute across lhi groups into A-fragment words:
        // after p32+p16: a0 -> word0 (keys 8lhi+0,1), b0 -> word2 (8lhi+4,5)
        //               a1 -> word1 (keys 8lhi+2,3), b1 -> word3 (8lhi+6,7)
        pl32swap(a0, b0); pl16swap(a0, b0);
        pl32swap(a1, b1); pl16swap(a1, b1);
        union { unsigned u[4]; s8v v; } pk;
        pk.u[0] = a0; pk.u[1] = a1; pk.u[2] = b0; pk.u[3] = b1;
        pa[mb][ksb] = pk.v;
      }
    }

    // O += P @ V
#pragma unroll
    for (int ks = 0; ks < 4; ++ks) {
      s8v vb2[4];
#pragma unroll
      for (int db = 0; db < 4; ++db)
        vb2[db] = *(const s8v*)&Vt[(db * 16 + llo) * 136 + ks * 32 + lhi * 8];
      __builtin_amdgcn_s_setprio(1);
#pragma unroll
      for (int mb = 0; mb < 2; ++mb)
#pragma unroll
        for (int db = 0; db < 4; ++db)
          accO[mb][db] = __builtin_amdgcn_mfma_f32_16x16x32_bf16(pa[mb][ks], vb2[db], accO[mb][db], 0, 0, 0);
      __builtin_amdgcn_s_setprio(0);
    }
    __syncthreads();  // before next stage overwrites Ks/Vt
  }

  // epilogue: reduce l across the 4 lhi key-groups, write bf16 partial acc + fp32 l
#pragma unroll
  for (int mb = 0; mb < 2; ++mb) {
    l_run[mb] += __shfl_xor(l_run[mb], 16, 64);
    l_run[mb] += __shfl_xor(l_run[mb], 32, 64);
  }
#pragma unroll
  for (int mb = 0; mb < 2; ++mb) {
    int row0 = qt * 128 + wid * 32 + mb * 16;
    size_t ibase = (size_t)(z * 32 + bh) * SEQ + row0;
    if (lane < 16) Pml[ibase + lane] = l_run[mb];   // lhi==0 lanes, query=row0+llo
#pragma unroll
    for (int r = 0; r < 4; ++r) {
      size_t irow = ibase + lhi * 4 + r;
#pragma unroll
      for (int db = 0; db < 4; ++db)
        Pacc[irow * 64 + db * 16 + llo] = f2bf(accO[mb][db][r]);
    }
  }
}

// ---------------- combine the two KV splits -> ctx (bf16 [tok][1024]), 8 B/thread (R10 form) ----------------
__global__ __launch_bounds__(256)
void attn_combine(const u16* __restrict__ Pacc, const float* __restrict__ Pml,
                  u16* __restrict__ ctx) {
  int g = blockIdx.x * 256 + threadIdx.x;  // quad id; 32*2048*16 total
  int d4 = g & 15;                         // quad of d (4 values, 8 B)
  int row = (g >> 4) & (SEQ - 1);
  int bh = g >> 15;
  int b = bh >> 4, h = bh & 15;
  size_t i0 = (size_t)bh * SEQ + row;
  size_t i1 = (size_t)(32 + bh) * SEQ + row;
  float inv = 1.0f / (Pml[i0] + Pml[i1]);
  uint2 pa = ((const uint2*)Pacc)[i0 * 16 + d4];
  uint2 pb = ((const uint2*)Pacc)[i1 * 16 + d4];
  float lo0 = u2f(pa.x << 16) + u2f(pb.x << 16);
  float hi0 = u2f(pa.x & 0xffff0000u) + u2f(pb.x & 0xffff0000u);
  float lo1 = u2f(pa.y << 16) + u2f(pb.y << 16);
  float hi1 = u2f(pa.y & 0xffff0000u) + u2f(pb.y & 0xffff0000u);
  uint2 o;
  o.x = (unsigned)f2bf(lo0 * inv) | ((unsigned)f2bf(hi0 * inv) << 16);
  o.y = (unsigned)f2bf(lo1 * inv) | ((unsigned)f2bf(hi1 * inv) << 16);
  ((uint2*)ctx)[(size_t)(b * SEQ + row) * (DMODEL / 4) + h * 16 + d4] = o;
}

// ---------------- orchestration ----------------
extern "C" void kernel_launch(void* const* d_in, const int* in_sizes, int n_in,
                              void* d_out, int out_size, void* d_ws, size_t ws_size,
                              hipStream_t stream) {
  const float* x   = (const float*)d_in[0];
  const float* Wq  = (const float*)d_in[1];  const float* bq = (const float*)d_in[2];
  const float* Wk  = (const float*)d_in[3];  const float* bk = (const float*)d_in[4];
  const float* Wv  = (const float*)d_in[5];  const float* bv = (const float*)d_in[6];
  const float* Wo  = (const float*)d_in[7];  const float* bo = (const float*)d_in[8];
  const float* W1  = (const float*)d_in[9];  const float* b1 = (const float*)d_in[10];
  const float* W2  = (const float*)d_in[11]; const float* b2 = (const float*)d_in[12];
  const float* l1a = (const float*)d_in[13]; const float* l1b = (const float*)d_in[14];
  const float* l2a = (const float*)d_in[15]; const float* l2b = (const float*)d_in[16];

  char* ws = (char*)d_ws;
  const size_t MB = 1u << 20;
  // weights 0-25 MB
  u16*   wqkv_t = (u16*)(ws + 0);          // [3072][1024] bf16: 6 MB
  u16*   wo_t   = (u16*)(ws + 6 * MB);     // [1024][1024]: 2 MB
  u16*   w1_t   = (u16*)(ws + 8 * MB);     // [4096][1024]: 8 MB
  u16*   w2_t   = (u16*)(ws + 16 * MB);    // [1024][4096]: 8 MB
  float* bqkv   = (float*)(ws + 24 * MB);  // 3072 floats
  // activations (time-multiplexed; max 97.5 MB — proven-safe footprint)
  u16*   xn1    = (u16*)(ws + 25 * MB);    // [4096][1024] bf16: 8 MB (ln1 -> QKV)
  u16*   qkv    = (u16*)(ws + 33 * MB);    // [4096][3072] bf16: 24 MB (QKV -> flash)
  u16*   Pacc   = (u16*)(ws + 57 * MB);    // [2][32][2048][64] bf16: 16 MB (flash -> combine)
  float* Pml    = (float*)(ws + 73 * MB);  // [2][32][2048] fp32: 0.5 MB
  u16*   ctx    = (u16*)(ws + 73 * MB + MB / 2);  // [4096][1024] bf16: 8 MB (combine -> O-proj)
  float* hgm    = (float*)(ws + 57 * MB);  // h fp32 16 MB (O-proj z0 direct; Pacc dead)
  float* po1    = (float*)(ws + 25 * MB);  // O-proj z1 partial fp32 16 MB (xn1+qkv dead)
  u16*   n2     = (u16*)(ws + 73 * MB + MB / 2);  // LN2 out 8 MB (ctx dead after O-proj)
  u16*   mid    = (u16*)(ws + 25 * MB);    // [4096][4096] bf16 32 MB (po1 dead)
  float* pf     = (float*)(ws + 73 * MB + MB / 2);  // FFN2 z1 partial 16 MB (n2/Pml dead)

  dim3 blk(256);

  // fused weight transposes + bias concat (Wq/bq pre-scaled by log2e for exp2-domain softmax)
  prep<<<dim3(6156), blk, 0, stream>>>(Wq, Wk, Wv, Wo, W1, W2, bq, bk, bv,
                                       wqkv_t, wo_t, w1_t, w2_t, bqkv);

  // LN1
  ln_bf16<<<NTOK, blk, 0, stream>>>(x, xn1, l1a, l1b);

  // fused QKV projection: [4096,1024] x [1024,3072] -> [4096,3072]  (256-tile, 192 blocks)
  gemm256<0, 1><<<dim3(12, 16), dim3(512), 0, stream>>>(xn1, wqkv_t, bqkv, qkv,
                                                        NTOK, QKVN, DMODEL);

  // attention, split-KV x2 -> bf16 partials, then combine
  flash_attn<<<dim3(16, 32, 2), blk, 0, stream>>>(qkv, Pacc, Pml);
  attn_combine<<<dim3(4096), blk, 0, stream>>>(Pacc, Pml, ctx);

  // O projection + residual, split-K x2 WITHOUT atomics:
  // z0 -> hgm = ctx@Wo(K-half0) + bo + x ; z1 -> po1 = ctx@Wo(K-half1)
  gemm_bt<0, 1, 0, 1><<<dim3(8, 32, 2), blk, 0, stream>>>(ctx, wo_t, bo, x, hgm, po1,
                                                          NTOK, DMODEL, DMODEL);

  // fused: h = hgm + po1 (in place, one ordered add -> deterministic); n2 = LN2(h)
  ln2_comb<<<NTOK, blk, 0, stream>>>(hgm, po1, n2, l2a, l2b);

  // FFN1: relu(n2 @ W1 + b1) -> bf16  (256-tile, 256 blocks = perfect fill)
  gemm256<1, 1><<<dim3(16, 16), dim3(512), 0, stream>>>(n2, w1_t, b1, mid,
                                                        NTOK, DFF, DMODEL);

  // FFN2 split-K x2 WITHOUT atomics: z0 -> d_out = mid@W2(half0) + b2 + h ; z1 -> pf
  gemm_bt<0, 1, 0, 1><<<dim3(8, 32, 2), blk, 0, stream>>>(mid, w2_t, b2, hgm,
                                                          (float*)d_out, pf,
                                                          NTOK, DMODEL, DFF);

  // d_out += pf  (single ordered add per element -> bitwise deterministic)
  add2<<<dim3(4096), blk, 0, stream>>>((float*)d_out, pf);
}